// Round 7
// baseline (374.850 us; speedup 1.0000x reference)
//
#include <hip/hip_runtime.h>

typedef unsigned short ushort_t;
typedef __attribute__((ext_vector_type(8))) short short8;
typedef __attribute__((ext_vector_type(4))) float float4v;
typedef __attribute__((ext_vector_type(2))) float float2v;

#define HW 16384
#define A_BINS 180
#define R_BINS 182
#define AP 188              // A padded by 4 each side
#define CCH 64
#define NB 4
#define NC 256              // NB*CCH, nc-major inner dim of hough buffers
#define MROWS (A_BINS * R_BINS)      // 32760
#define MPROWS (AP * R_BINS)         // 34216
#define PADPX HW            // dummy pixel id -> zeroed row in xT
#define PLSTRIDE 17664      // per-angle plist stride (HW + 182*7 rounded up, %8==0)
#define ST_ROWB 528         // idht staging row stride in bytes (512 + 16 pad)

static __device__ __forceinline__ float b2f(ushort_t u) {
    union { unsigned u32; float f; } c; c.u32 = ((unsigned)u) << 16; return c.f;
}
static __device__ __forceinline__ float u2f(unsigned u) {
    union { unsigned u32; float f; } c; c.u32 = u; return c.f;
}
static __device__ __forceinline__ ushort_t f2b(float f) {
    union { float f; unsigned u; } c; c.f = f;
    unsigned r = c.u + 0x7fffu + ((c.u >> 16) & 1u);   // RNE
    return (ushort_t)(r >> 16);
}
// packed f32 accumulate: a += {lo(u)<<16, hi(u)} via one VOP3P v_pk_add_f32
static __device__ __forceinline__ void pkaccu(float2v& a, unsigned u) {
    float2v b; b.x = u2f(u << 16); b.y = u2f(u & 0xffff0000u);
    asm("v_pk_add_f32 %0, %1, %0" : "+v"(a) : "v"(b));
}

// ==== fused prep: transpose (blk<1024) | setup (1024..1336) | csr (1337..1516) ====
union PrepShared {
    float tile[64][65];                // 16.6 KB (transpose)
    struct {                           // 42.6 KB (csr)
        int hist[4][R_BINS];
        int tot[R_BINS];
        int offl[R_BINS + 1];
        int cur[4][R_BINS];
        ushort_t sp[PLSTRIDE];
    } c;
};

__global__ __launch_bounds__(256) void k_prep(const float* __restrict__ x,
                                              ushort_t* __restrict__ xT,
                                              ushort_t* __restrict__ ht0,
                                              ushort_t* __restrict__ bufA,
                                              ushort_t* __restrict__ bufB,
                                              const float* __restrict__ w2,
                                              const float* __restrict__ w3,
                                              ushort_t* __restrict__ w2b,
                                              ushort_t* __restrict__ w3b,
                                              const int* __restrict__ rho,
                                              int* __restrict__ offs,
                                              ushort_t* __restrict__ plist) {
    __shared__ PrepShared u;
    int blk = blockIdx.x, t = threadIdx.x;
    if (blk < 1024) {                  // ---------------- transpose ----------------
        int lane = t & 63, g = t >> 6;
        int pBase = (blk & 255) * 64;
        int ncBase = (blk >> 8) * 64;
#pragma unroll
        for (int i = 0; i < 16; ++i) {
            int ncl = g + i * 4;
            u.tile[ncl][lane] = x[(size_t)(ncBase + ncl) * HW + pBase + lane];
        }
        __syncthreads();
#pragma unroll
        for (int i = 0; i < 16; ++i) {
            int pl = g + i * 4;
            xT[(size_t)(pBase + pl) * 256 + ncBase + lane] = f2b(u.tile[lane][pl]);
        }
        return;
    }
    if (blk < 1337) {                  // ---------------- setup ----------------
        int sblk = blk - 1024;         // 0..312
        if (sblk == 312) {             // zero the dummy-pixel row of xT
            if (t < 64) ((uint2*)(xT + (size_t)PADPX * NC))[t] = (uint2){0u, 0u};
            return;
        }
        if (sblk < 24) {
            int b = sblk >> 3, j = sblk & 7;
            int ap = (j < 4) ? j : (184 + (j - 4));
            ushort_t* base = (b == 0 ? ht0 : (b == 1 ? bufA : bufB));
            uint4* p = (uint4*)(base + (size_t)ap * (R_BINS * NC));
            int n16 = R_BINS * NC / 8;
            for (int i = t; i < n16; i += 256) p[i] = (uint4){0, 0, 0, 0};
            return;
        }
        int rep = sblk - 24;               // 0..287
        const float* w = (rep >= 144) ? w3 : w2;
        ushort_t* wb = (rep >= 144) ? w3b : w2b;
        int idx = (rep % 144) * 256 + t;   // 0..36863
        int j = idx & 7;
        int lane = (idx >> 3) & 63;
        int cot = (idx >> 9) & 3;
        int h = (idx >> 11) & 1;
        int k = idx >> 12;
        int co = cot * 16 + (lane & 15);
        int ci = h * 32 + (lane >> 4) * 8 + j;
        wb[idx] = f2b(w[(co * 64 + ci) * 9 + k]);
        return;
    }
    // ---------------- csr: bin -> pixel list, bins padded to %8 ----------------
    int a = blk - 1337, lane = t & 63, wv = t >> 6;
    for (int i = t; i < 4 * R_BINS; i += 256) ((int*)u.c.hist)[i] = 0;
    __syncthreads();
    const int* rA = rho + (size_t)a * HW;
#pragma unroll 4
    for (int i = 0; i < 64; ++i) {
        int r = rA[t + i * 256];
        atomicAdd(&u.c.hist[wv][r], 1);
    }
    __syncthreads();
    if (t < R_BINS) u.c.tot[t] = u.c.hist[0][t] + u.c.hist[1][t] + u.c.hist[2][t] + u.c.hist[3][t];
    __syncthreads();
    if (wv == 0) {                     // wave-parallel exclusive scan of PADDED counts
        int b0 = lane * 3;
        int c0 = (b0     < R_BINS) ? ((u.c.tot[b0]     + 7) & ~7) : 0;
        int c1 = (b0 + 1 < R_BINS) ? ((u.c.tot[b0 + 1] + 7) & ~7) : 0;
        int c2 = (b0 + 2 < R_BINS) ? ((u.c.tot[b0 + 2] + 7) & ~7) : 0;
        int sum = c0 + c1 + c2, inc = sum;
#pragma unroll
        for (int d = 1; d < 64; d <<= 1) {
            int vv = __shfl_up(inc, d);
            if (lane >= d) inc += vv;
        }
        int excl = inc - sum;
        if (b0     < R_BINS) u.c.offl[b0]     = excl;
        if (b0 + 1 < R_BINS) u.c.offl[b0 + 1] = excl + c0;
        if (b0 + 2 < R_BINS) u.c.offl[b0 + 2] = excl + c0 + c1;
        if (lane == 63) u.c.offl[R_BINS] = inc;
    }
    __syncthreads();
    if (t < R_BINS) {
        int b = u.c.offl[t];
        u.c.cur[0][t] = b; b += u.c.hist[0][t];
        u.c.cur[1][t] = b; b += u.c.hist[1][t];
        u.c.cur[2][t] = b; b += u.c.hist[2][t];
        u.c.cur[3][t] = b;
    }
    if (t <= R_BINS) offs[a * (R_BINS + 1) + t] = u.c.offl[t];
    __syncthreads();
#pragma unroll 4
    for (int i = 0; i < 64; ++i) {
        int p = t + i * 256;
        int r = rA[p];
        int pos = atomicAdd(&u.c.cur[wv][r], 1);
        u.c.sp[pos] = (ushort_t)p;
    }
    __syncthreads();
    if (t < R_BINS) {                  // fill pad slots with dummy pixel id
        int base = u.c.offl[t] + u.c.tot[t];
        int pend = u.c.offl[t + 1];
        for (int k = base; k < pend; ++k) u.c.sp[k] = (ushort_t)PADPX;
    }
    __syncthreads();
    int len = u.c.offl[R_BINS];        // multiple of 8
    const uint4* spv = (const uint4*)u.c.sp;
    uint4* plv = (uint4*)(plist + (size_t)a * PLSTRIDE);
    for (int i = t; i < len / 8; i += 256) plv[i] = spv[i];
}

// ---- DHT gather v7 (measured 75.6 us, unchanged) ----
__global__ __launch_bounds__(256, 4) void k_dht_g7(const ushort_t* __restrict__ xT,
                                                   const int* __restrict__ offs,
                                                   const ushort_t* __restrict__ plist,
                                                   ushort_t* __restrict__ ht0) {
    int ax = blockIdx.x;               // 0..359
    int a = ax >> 1, half = ax & 1;    // v5 mapping (measured-good)
    int part = blockIdx.y;             // 0..15
    int t = threadIdx.x, lane = t & 63, wv = t >> 6;
    int wslot = part * 4 + wv;         // 0..63
    int nl = lane & 15;                // 8-nc chunk within the 128-nc half
    unsigned lhb = (unsigned)nl * 16;  // byte offset of my 8 nc
    unsigned shsel = (lane & 16) ? 16u : 0u;
    const char* xh = (const char*)xT + half * 256;   // byte base of my half
    const uint4* plq = (const uint4*)(plist + (size_t)a * PLSTRIDE);
    const int* offA = offs + a * (R_BINS + 1);
    size_t obase = (size_t)(a + 4) * (R_BINS * NC) + half * 128;
    for (int r = wslot; r < R_BINS; r += 64) {
        int off = __builtin_amdgcn_readfirstlane(offA[r]);
        int end = __builtin_amdgcn_readfirstlane(offA[r + 1]);
        float2v ac0 = (float2v){0.f, 0.f}, ac1 = (float2v){0.f, 0.f};
        float2v ac2 = (float2v){0.f, 0.f}, ac3 = (float2v){0.f, 0.f};
        int j = off;
        if (j < end) {
            uint4 w = plq[j >> 3];
            for (;;) {
                int jn = j + 8;
                uint4 wn = (uint4){0u, 0u, 0u, 0u};
                bool more = jn < end;
                if (more) wn = plq[jn >> 3];
                {   // pixels j..j+3: ids in w.x (j,j+1), w.y (j+2,j+3)
                    unsigned we = (lane & 32) ? w.y : w.x;
                    unsigned ps = (we >> shsel) & 0xffffu;
                    uint4 u = *(const uint4*)(xh + ((size_t)ps << 9) + lhb);
                    pkaccu(ac0, u.x); pkaccu(ac1, u.y);
                    pkaccu(ac2, u.z); pkaccu(ac3, u.w);
                }
                {   // pixels j+4..j+7: ids in w.z, w.w
                    unsigned we = (lane & 32) ? w.w : w.z;
                    unsigned ps = (we >> shsel) & 0xffffu;
                    uint4 u = *(const uint4*)(xh + ((size_t)ps << 9) + lhb);
                    pkaccu(ac0, u.x); pkaccu(ac1, u.y);
                    pkaccu(ac2, u.z); pkaccu(ac3, u.w);
                }
                if (!more) break;
                w = wn; j = jn;
            }
        }
        // combine across the 4 pixel-residue lane groups (2 shfl_xor rounds)
        float rs[8] = {ac0.x, ac0.y, ac1.x, ac1.y, ac2.x, ac2.y, ac3.x, ac3.y};
#pragma unroll
        for (int c = 0; c < 8; ++c) {
            rs[c] += __shfl_xor(rs[c], 16);
            rs[c] += __shfl_xor(rs[c], 32);
        }
        if (lane < 16) {
            uint4 o;
            o.x = (unsigned)f2b(rs[0]) | ((unsigned)f2b(rs[1]) << 16);
            o.y = (unsigned)f2b(rs[2]) | ((unsigned)f2b(rs[3]) << 16);
            o.z = (unsigned)f2b(rs[4]) | ((unsigned)f2b(rs[5]) << 16);
            o.w = (unsigned)f2b(rs[6]) | ((unsigned)f2b(rs[7]) << 16);
            *(uint4*)(ht0 + obase + (size_t)r * NC + nl * 8) = o;
        }
    }
}

// ---- depthwise (9,1) conv + bias + relu: register sliding window along a ----
__global__ __launch_bounds__(256) void k_conv1(const ushort_t* __restrict__ ht0,
                                               const float* __restrict__ w1,
                                               const float* __restrict__ b1,
                                               ushort_t* __restrict__ bufA) {
    int t = threadIdx.x, c = t & 63;
    int r = blockIdx.x;              // 0..181
    int a0 = blockIdx.y * 30;        // output angle base (real coords)
    float wr[9];
#pragma unroll
    for (int k = 0; k < 9; ++k) wr[k] = w1[c * 9 + k];
    float bb = b1[c];
    const ushort_t* ip = ht0 + ((size_t)a0 * R_BINS + r) * NC + t;
    float v[38];
#pragma unroll
    for (int j = 0; j < 38; ++j) v[j] = b2f(ip[(size_t)j * (R_BINS * NC)]);
    ushort_t* op = bufA + ((size_t)(a0 + 4) * R_BINS + r) * NC + t;
#pragma unroll
    for (int i = 0; i < 30; ++i) {
        float s = bb;
#pragma unroll
        for (int k = 0; k < 9; ++k) s = fmaf(v[i + k], wr[k], s);
        op[(size_t)i * (R_BINS * NC)] = f2b(fmaxf(s, 0.f));
    }
}

// ---- dense (9,1) conv as MFMA GEMM: B staged in LDS, 64 rows/wave ----
__global__ __launch_bounds__(256) void k_gemm(const ushort_t* __restrict__ in,
                                              const ushort_t* __restrict__ wb,
                                              const float* __restrict__ bias,
                                              ushort_t* __restrict__ out,
                                              int outRowOff) {
    __shared__ ushort_t Bs[36864];   // 73.7 KB -> 2 blocks/CU
    int t = threadIdx.x, lane = t & 63, wv = t >> 6;
    {
        const uint4* src = (const uint4*)wb;
        uint4* dst = (uint4*)Bs;
        for (int i = t; i < 36864 / 8; i += 256) dst[i] = src[i];
    }
    __syncthreads();
    int m = lane & 15, q = lane >> 4;
    int n = blockIdx.y;
    int rowBase = blockIdx.x * 256 + wv * 64;
    const ushort_t* inN = in + n * 64;
    size_t rof[4];
#pragma unroll
    for (int tl = 0; tl < 4; ++tl) {
        int row = rowBase + tl * 16 + m;
        int rowc = row < MROWS ? row : (MROWS - 1);
        rof[tl] = (size_t)rowc * NC;
    }
    float4v acc[4][4];
#pragma unroll
    for (int tl = 0; tl < 4; ++tl)
#pragma unroll
        for (int i = 0; i < 4; ++i) acc[tl][i] = (float4v){0.f, 0.f, 0.f, 0.f};

#pragma unroll
    for (int k = 0; k < 9; ++k) {
#pragma unroll
        for (int h = 0; h < 2; ++h) {
            const ushort_t* base = inN + (size_t)k * (R_BINS * NC) + h * 32 + q * 8;
            short8 af0 = *(const short8*)(base + rof[0]);
            short8 af1 = *(const short8*)(base + rof[1]);
            short8 af2 = *(const short8*)(base + rof[2]);
            short8 af3 = *(const short8*)(base + rof[3]);
            const ushort_t* bl = Bs + (size_t)((k * 2 + h) * 4) * 512 + lane * 8;
            short8 b0 = *(const short8*)(bl);
            short8 b1v = *(const short8*)(bl + 512);
            short8 b2v = *(const short8*)(bl + 1024);
            short8 b3v = *(const short8*)(bl + 1536);
            acc[0][0] = __builtin_amdgcn_mfma_f32_16x16x32_bf16(af0, b0, acc[0][0], 0, 0, 0);
            acc[0][1] = __builtin_amdgcn_mfma_f32_16x16x32_bf16(af0, b1v, acc[0][1], 0, 0, 0);
            acc[0][2] = __builtin_amdgcn_mfma_f32_16x16x32_bf16(af0, b2v, acc[0][2], 0, 0, 0);
            acc[0][3] = __builtin_amdgcn_mfma_f32_16x16x32_bf16(af0, b3v, acc[0][3], 0, 0, 0);
            acc[1][0] = __builtin_amdgcn_mfma_f32_16x16x32_bf16(af1, b0, acc[1][0], 0, 0, 0);
            acc[1][1] = __builtin_amdgcn_mfma_f32_16x16x32_bf16(af1, b1v, acc[1][1], 0, 0, 0);
            acc[1][2] = __builtin_amdgcn_mfma_f32_16x16x32_bf16(af1, b2v, acc[1][2], 0, 0, 0);
            acc[1][3] = __builtin_amdgcn_mfma_f32_16x16x32_bf16(af1, b3v, acc[1][3], 0, 0, 0);
            acc[2][0] = __builtin_amdgcn_mfma_f32_16x16x32_bf16(af2, b0, acc[2][0], 0, 0, 0);
            acc[2][1] = __builtin_amdgcn_mfma_f32_16x16x32_bf16(af2, b1v, acc[2][1], 0, 0, 0);
            acc[2][2] = __builtin_amdgcn_mfma_f32_16x16x32_bf16(af2, b2v, acc[2][2], 0, 0, 0);
            acc[2][3] = __builtin_amdgcn_mfma_f32_16x16x32_bf16(af2, b3v, acc[2][3], 0, 0, 0);
            acc[3][0] = __builtin_amdgcn_mfma_f32_16x16x32_bf16(af3, b0, acc[3][0], 0, 0, 0);
            acc[3][1] = __builtin_amdgcn_mfma_f32_16x16x32_bf16(af3, b1v, acc[3][1], 0, 0, 0);
            acc[3][2] = __builtin_amdgcn_mfma_f32_16x16x32_bf16(af3, b2v, acc[3][2], 0, 0, 0);
            acc[3][3] = __builtin_amdgcn_mfma_f32_16x16x32_bf16(af3, b3v, acc[3][3], 0, 0, 0);
        }
    }

    ushort_t* outN = out + n * 64;
#pragma unroll
    for (int tl = 0; tl < 4; ++tl) {
#pragma unroll
        for (int cot = 0; cot < 4; ++cot) {
            int co = cot * 16 + m;
            float bv = bias[co];
#pragma unroll
            for (int i = 0; i < 4; ++i) {
                int rowD = rowBase + tl * 16 + q * 4 + i;
                float v = fmaxf(acc[tl][cot][i] + bv, 0.f);
                if (rowD < MROWS) outN[(size_t)(rowD + outRowOff) * NC + co] = f2b(v);
            }
        }
    }
}

// ---- inverse DHT v9: contiguous bin-range staging, depth-2 prefetch (3 LDS
// buffers), conflict-free read map. Lane (px=t>>4, ncg=t&15) reads CONSECUTIVE
// 16B chunks (ncg*16) of the row's two 256B halves; rows padded to 528 B so
// adjacent-row px-quads shift banks. Global loads for a+2 issued at iter a ->
// a full iteration before their ds_write vmcnt wait.
union SharedIdht {
    struct {
        int rhoL[A_BINS * 32];          // 23040 B, [a][px]
        ushort_t st[3][34 * 264];       // 3 x 17952 B staging (528 B rows)
    } s;                                // 76896 B live during loop
    float tile[256 * 33];               // 33792 B, [nc][px] (after loop)
};

__global__ __launch_bounds__(512, 2) void k_idht(const ushort_t* __restrict__ buf3,
                                                 const int* __restrict__ rho,
                                                 float* __restrict__ outp) {
    __shared__ SharedIdht u;
    int t = threadIdx.x;
    int P0 = blockIdx.x * 32;
    int px = t >> 4;                    // 0..31
    int ncg = t & 15;                   // 16B chunk within 256B row-half
    for (int i = t; i < A_BINS * 32; i += 512) {
        int a = i >> 5, p = i & 31;
        u.s.rhoL[i] = rho[(size_t)a * HW + P0 + p];
    }
    __syncthreads();                    // rhoL ready
    float2v acc[8];
#pragma unroll
    for (int i = 0; i < 8; ++i) acc[i] = (float2v){0.f, 0.f};

    {   // prologue: stage angle 0 directly
        int r0 = u.s.rhoL[0], r31 = u.s.rhoL[31];
        int rmin0 = r0 < r31 ? r0 : r31;
        int cnt0 = (r0 < r31 ? r31 - r0 : r0 - r31) + 1;
        const uint4* src = (const uint4*)(buf3 + (size_t)rmin0 * NC);
        for (int i = t; i < cnt0 * 32; i += 512) {
            uint4 v = src[i];
            *(uint4*)((char*)u.s.st[0] + (i >> 5) * ST_ROWB + ((i & 31) << 4)) = v;
        }
    }
    // prologue: issue reg loads for angle 1
    uint4 R1a = (uint4){0,0,0,0}, R1b = (uint4){0,0,0,0}, R1c = (uint4){0,0,0,0};
    int limR1 = 0;
    {
        int r0 = u.s.rhoL[32], r31 = u.s.rhoL[63];
        int rmin = r0 < r31 ? r0 : r31;
        limR1 = ((r0 < r31 ? r31 - r0 : r0 - r31) + 1) * 32;
        const uint4* src = (const uint4*)(buf3 + (size_t)(R_BINS * NC) + (size_t)rmin * NC);
        if (t < limR1)        R1a = src[t];
        if (t + 512 < limR1)  R1b = src[t + 512];
        if (t + 1024 < limR1) R1c = src[t + 1024];
    }
    __syncthreads();                    // st[0] visible

    int bc = 0;                         // current buffer = a % 3
    for (int a = 0; a < A_BINS; ++a) {
        // issue reg loads for a+2 (consumed two iterations later)
        uint4 R2a = (uint4){0,0,0,0}, R2b = (uint4){0,0,0,0}, R2c = (uint4){0,0,0,0};
        int limR2 = 0;
        if (a + 2 < A_BINS) {
            int r0 = u.s.rhoL[(a + 2) * 32], r31 = u.s.rhoL[(a + 2) * 32 + 31];
            int rmin = r0 < r31 ? r0 : r31;
            limR2 = ((r0 < r31 ? r31 - r0 : r0 - r31) + 1) * 32;
            const uint4* src = (const uint4*)(buf3 + (size_t)(a + 2) * (R_BINS * NC)
                                              + (size_t)rmin * NC);
            if (t < limR2)        R2a = src[t];
            if (t + 512 < limR2)  R2b = src[t + 512];
            if (t + 1024 < limR2) R2c = src[t + 1024];
        }
        // accumulate(a) from st[bc]
        {
            int r0 = u.s.rhoL[a * 32], r31 = u.s.rhoL[a * 32 + 31];
            int rmin = r0 < r31 ? r0 : r31;
            int row = u.s.rhoL[a * 32 + px] - rmin;
            const char* rowp = (const char*)u.s.st[bc] + row * ST_ROWB + (ncg << 4);
            uint4 v0 = *(const uint4*)rowp;          // nc = ncg*8 .. +7
            uint4 v1 = *(const uint4*)(rowp + 256);  // nc = 128 + ncg*8 .. +7
            pkaccu(acc[0], v0.x); pkaccu(acc[1], v0.y);
            pkaccu(acc[2], v0.z); pkaccu(acc[3], v0.w);
            pkaccu(acc[4], v1.x); pkaccu(acc[5], v1.y);
            pkaccu(acc[6], v1.z); pkaccu(acc[7], v1.w);
        }
        // write regs (angle a+1, issued last iter) into st[(a+1)%3]
        int bn = bc + 1; if (bn == 3) bn = 0;
        if (a + 1 < A_BINS) {
            char* dst = (char*)u.s.st[bn];
            if (t < limR1)
                *(uint4*)(dst + (t >> 5) * ST_ROWB + ((t & 31) << 4)) = R1a;
            if (t + 512 < limR1)
                *(uint4*)(dst + ((t + 512) >> 5) * ST_ROWB + (((t + 512) & 31) << 4)) = R1b;
            if (t + 1024 < limR1)
                *(uint4*)(dst + ((t + 1024) >> 5) * ST_ROWB + (((t + 1024) & 31) << 4)) = R1c;
        }
        R1a = R2a; R1b = R2b; R1c = R2c; limR1 = limR2;
        bc = bn;
        __syncthreads();
    }

    // transpose via LDS tile (aliases rhoL/st — dead after final barrier)
#pragma unroll
    for (int k = 0; k < 4; ++k) {
        int nc = ncg * 8 + 2 * k;
        u.tile[nc * 33 + px] = acc[k].x;
        u.tile[(nc + 1) * 33 + px] = acc[k].y;
    }
#pragma unroll
    for (int k = 0; k < 4; ++k) {
        int nc = 128 + ncg * 8 + 2 * k;
        u.tile[nc * 33 + px] = acc[4 + k].x;
        u.tile[(nc + 1) * 33 + px] = acc[4 + k].y;
    }
    __syncthreads();
    int px2 = t & 31, nc0 = t >> 5;     // nc0 0..15
    float* on = outp + P0 + px2;
#pragma unroll
    for (int k = 0; k < 16; ++k) {
        int nc = nc0 + k * 16;
        on[(size_t)nc * HW] = u.tile[nc * 33 + px2];
    }
}

extern "C" void kernel_launch(void* const* d_in, const int* in_sizes, int n_in,
                              void* d_out, int out_size, void* d_ws, size_t ws_size,
                              hipStream_t stream) {
    const float* x   = (const float*)d_in[0];
    const int*   rho = (const int*)d_in[1];
    const float* w1  = (const float*)d_in[2];
    const float* b1  = (const float*)d_in[3];
    const float* w2  = (const float*)d_in[4];
    const float* b2  = (const float*)d_in[5];
    const float* w3  = (const float*)d_in[6];
    const float* b3  = (const float*)d_in[7];
    float* outp = (float*)d_out;

    char* ws = (char*)d_ws;
    size_t off = 0;
    auto alloc = [&](size_t bytes) -> void* {
        void* p = ws + off;
        off = (off + bytes + 255) & ~(size_t)255;
        return p;
    };
    ushort_t* xT    = (ushort_t*)alloc((size_t)(HW + 8) * NC * 2);       // 8 MB + pad row
    ushort_t* ht0   = (ushort_t*)alloc((size_t)AP * R_BINS * NC * 2);    // 17.5 MB
    ushort_t* bufA  = (ushort_t*)alloc((size_t)AP * R_BINS * NC * 2);    // 17.5 MB
    ushort_t* bufB  = (ushort_t*)alloc((size_t)AP * R_BINS * NC * 2);    // 17.5 MB
    ushort_t* buf3  = (ushort_t*)alloc((size_t)A_BINS * R_BINS * NC * 2);// 16.8 MB
    ushort_t* w2b   = (ushort_t*)alloc(36864 * 2);
    ushort_t* w3b   = (ushort_t*)alloc(36864 * 2);
    int*      offs  = (int*)alloc((size_t)A_BINS * (R_BINS + 1) * 4);    // 132 KB
    ushort_t* plist = (ushort_t*)alloc((size_t)A_BINS * PLSTRIDE * 2);   // 6.4 MB

    k_prep<<<1517, 256, 0, stream>>>(x, xT, ht0, bufA, bufB, w2, w3, w2b, w3b,
                                     rho, offs, plist);
    k_dht_g7<<<dim3(360, 16), 256, 0, stream>>>(xT, offs, plist, ht0);
    k_conv1<<<dim3(R_BINS, 6), 256, 0, stream>>>(ht0, w1, b1, bufA);
    k_gemm<<<dim3(128, NB), 256, 0, stream>>>(bufA, w2b, b2, bufB, 728);
    k_gemm<<<dim3(128, NB), 256, 0, stream>>>(bufB, w3b, b3, buf3, 0);
    k_idht<<<dim3(512), 512, 0, stream>>>(buf3, rho, outp);
}

// Round 9
// 312.893 us; speedup vs baseline: 1.1980x; 1.1980x over previous
//
#include <hip/hip_runtime.h>

typedef unsigned short ushort_t;
typedef __attribute__((ext_vector_type(8))) short short8;
typedef __attribute__((ext_vector_type(4))) float float4v;
typedef __attribute__((ext_vector_type(2))) float float2v;

#define HW 16384
#define A_BINS 180
#define R_BINS 182
#define AP 188              // A padded by 4 each side
#define CCH 64
#define NB 4
#define NC 256              // NB*CCH, nc-major inner dim of hough buffers
#define MROWS (A_BINS * R_BINS)      // 32760
#define MPROWS (AP * R_BINS)         // 34216
#define PADPX HW            // dummy pixel id -> zeroed row in xT
#define PLSTRIDE 17664      // per-angle plist stride (HW + 182*7 rounded up, %8==0)

static __device__ __forceinline__ float b2f(ushort_t u) {
    union { unsigned u32; float f; } c; c.u32 = ((unsigned)u) << 16; return c.f;
}
static __device__ __forceinline__ float u2f(unsigned u) {
    union { unsigned u32; float f; } c; c.u32 = u; return c.f;
}
static __device__ __forceinline__ ushort_t f2b(float f) {
    union { float f; unsigned u; } c; c.f = f;
    unsigned r = c.u + 0x7fffu + ((c.u >> 16) & 1u);   // RNE
    return (ushort_t)(r >> 16);
}
// packed f32 accumulate: a += {lo(u)<<16, hi(u)} via one VOP3P v_pk_add_f32
static __device__ __forceinline__ void pkaccu(float2v& a, unsigned u) {
    float2v b; b.x = u2f(u << 16); b.y = u2f(u & 0xffff0000u);
    asm("v_pk_add_f32 %0, %1, %0" : "+v"(a) : "v"(b));
}

// ==== fused prep: transpose (blk<1024) | setup (1024..1336) | csr (1337..1516) ====
union PrepShared {
    float tile[64][65];                // 16.6 KB (transpose)
    struct {                           // 42.6 KB (csr)
        int hist[4][R_BINS];
        int tot[R_BINS];
        int offl[R_BINS + 1];
        int cur[4][R_BINS];
        ushort_t sp[PLSTRIDE];
    } c;
};

__global__ __launch_bounds__(256) void k_prep(const float* __restrict__ x,
                                              ushort_t* __restrict__ xT,
                                              ushort_t* __restrict__ ht0,
                                              ushort_t* __restrict__ bufA,
                                              ushort_t* __restrict__ bufB,
                                              const float* __restrict__ w2,
                                              const float* __restrict__ w3,
                                              ushort_t* __restrict__ w2b,
                                              ushort_t* __restrict__ w3b,
                                              const int* __restrict__ rho,
                                              int* __restrict__ offs,
                                              ushort_t* __restrict__ plist) {
    __shared__ PrepShared u;
    int blk = blockIdx.x, t = threadIdx.x;
    if (blk < 1024) {                  // ---------------- transpose ----------------
        int lane = t & 63, g = t >> 6;
        int pBase = (blk & 255) * 64;
        int ncBase = (blk >> 8) * 64;
#pragma unroll
        for (int i = 0; i < 16; ++i) {
            int ncl = g + i * 4;
            u.tile[ncl][lane] = x[(size_t)(ncBase + ncl) * HW + pBase + lane];
        }
        __syncthreads();
#pragma unroll
        for (int i = 0; i < 16; ++i) {
            int pl = g + i * 4;
            xT[(size_t)(pBase + pl) * 256 + ncBase + lane] = f2b(u.tile[lane][pl]);
        }
        return;
    }
    if (blk < 1337) {                  // ---------------- setup ----------------
        int sblk = blk - 1024;         // 0..312
        if (sblk == 312) {             // zero the dummy-pixel row of xT
            if (t < 64) ((uint2*)(xT + (size_t)PADPX * NC))[t] = (uint2){0u, 0u};
            return;
        }
        if (sblk < 24) {
            int b = sblk >> 3, j = sblk & 7;
            int ap = (j < 4) ? j : (184 + (j - 4));
            ushort_t* base = (b == 0 ? ht0 : (b == 1 ? bufA : bufB));
            uint4* p = (uint4*)(base + (size_t)ap * (R_BINS * NC));
            int n16 = R_BINS * NC / 8;
            for (int i = t; i < n16; i += 256) p[i] = (uint4){0, 0, 0, 0};
            return;
        }
        int rep = sblk - 24;               // 0..287
        const float* w = (rep >= 144) ? w3 : w2;
        ushort_t* wb = (rep >= 144) ? w3b : w2b;
        int idx = (rep % 144) * 256 + t;   // 0..36863
        int j = idx & 7;
        int lane = (idx >> 3) & 63;
        int cot = (idx >> 9) & 3;
        int h = (idx >> 11) & 1;
        int k = idx >> 12;
        int co = cot * 16 + (lane & 15);
        int ci = h * 32 + (lane >> 4) * 8 + j;
        wb[idx] = f2b(w[(co * 64 + ci) * 9 + k]);
        return;
    }
    // ---------------- csr: bin -> pixel list, bins padded to %8 ----------------
    int a = blk - 1337, lane = t & 63, wv = t >> 6;
    for (int i = t; i < 4 * R_BINS; i += 256) ((int*)u.c.hist)[i] = 0;
    __syncthreads();
    const int* rA = rho + (size_t)a * HW;
#pragma unroll 4
    for (int i = 0; i < 64; ++i) {
        int r = rA[t + i * 256];
        atomicAdd(&u.c.hist[wv][r], 1);
    }
    __syncthreads();
    if (t < R_BINS) u.c.tot[t] = u.c.hist[0][t] + u.c.hist[1][t] + u.c.hist[2][t] + u.c.hist[3][t];
    __syncthreads();
    if (wv == 0) {                     // wave-parallel exclusive scan of PADDED counts
        int b0 = lane * 3;
        int c0 = (b0     < R_BINS) ? ((u.c.tot[b0]     + 7) & ~7) : 0;
        int c1 = (b0 + 1 < R_BINS) ? ((u.c.tot[b0 + 1] + 7) & ~7) : 0;
        int c2 = (b0 + 2 < R_BINS) ? ((u.c.tot[b0 + 2] + 7) & ~7) : 0;
        int sum = c0 + c1 + c2, inc = sum;
#pragma unroll
        for (int d = 1; d < 64; d <<= 1) {
            int vv = __shfl_up(inc, d);
            if (lane >= d) inc += vv;
        }
        int excl = inc - sum;
        if (b0     < R_BINS) u.c.offl[b0]     = excl;
        if (b0 + 1 < R_BINS) u.c.offl[b0 + 1] = excl + c0;
        if (b0 + 2 < R_BINS) u.c.offl[b0 + 2] = excl + c0 + c1;
        if (lane == 63) u.c.offl[R_BINS] = inc;
    }
    __syncthreads();
    if (t < R_BINS) {
        int b = u.c.offl[t];
        u.c.cur[0][t] = b; b += u.c.hist[0][t];
        u.c.cur[1][t] = b; b += u.c.hist[1][t];
        u.c.cur[2][t] = b; b += u.c.hist[2][t];
        u.c.cur[3][t] = b;
    }
    if (t <= R_BINS) offs[a * (R_BINS + 1) + t] = u.c.offl[t];
    __syncthreads();
#pragma unroll 4
    for (int i = 0; i < 64; ++i) {
        int p = t + i * 256;
        int r = rA[p];
        int pos = atomicAdd(&u.c.cur[wv][r], 1);
        u.c.sp[pos] = (ushort_t)p;
    }
    __syncthreads();
    if (t < R_BINS) {                  // fill pad slots with dummy pixel id
        int base = u.c.offl[t] + u.c.tot[t];
        int pend = u.c.offl[t + 1];
        for (int k = base; k < pend; ++k) u.c.sp[k] = (ushort_t)PADPX;
    }
    __syncthreads();
    int len = u.c.offl[R_BINS];        // multiple of 8
    const uint4* spv = (const uint4*)u.c.sp;
    uint4* plv = (uint4*)(plist + (size_t)a * PLSTRIDE);
    for (int i = t; i < len / 8; i += 256) plv[i] = spv[i];
}

// ---- DHT gather v7 (measured 75.6 us, unchanged) ----
__global__ __launch_bounds__(256, 4) void k_dht_g7(const ushort_t* __restrict__ xT,
                                                   const int* __restrict__ offs,
                                                   const ushort_t* __restrict__ plist,
                                                   ushort_t* __restrict__ ht0) {
    int ax = blockIdx.x;               // 0..359
    int a = ax >> 1, half = ax & 1;    // v5 mapping (measured-good)
    int part = blockIdx.y;             // 0..15
    int t = threadIdx.x, lane = t & 63, wv = t >> 6;
    int wslot = part * 4 + wv;         // 0..63
    int nl = lane & 15;                // 8-nc chunk within the 128-nc half
    unsigned lhb = (unsigned)nl * 16;  // byte offset of my 8 nc
    unsigned shsel = (lane & 16) ? 16u : 0u;
    const char* xh = (const char*)xT + half * 256;   // byte base of my half
    const uint4* plq = (const uint4*)(plist + (size_t)a * PLSTRIDE);
    const int* offA = offs + a * (R_BINS + 1);
    size_t obase = (size_t)(a + 4) * (R_BINS * NC) + half * 128;
    for (int r = wslot; r < R_BINS; r += 64) {
        int off = __builtin_amdgcn_readfirstlane(offA[r]);
        int end = __builtin_amdgcn_readfirstlane(offA[r + 1]);
        float2v ac0 = (float2v){0.f, 0.f}, ac1 = (float2v){0.f, 0.f};
        float2v ac2 = (float2v){0.f, 0.f}, ac3 = (float2v){0.f, 0.f};
        int j = off;
        if (j < end) {
            uint4 w = plq[j >> 3];
            for (;;) {
                int jn = j + 8;
                uint4 wn = (uint4){0u, 0u, 0u, 0u};
                bool more = jn < end;
                if (more) wn = plq[jn >> 3];
                {   // pixels j..j+3: ids in w.x (j,j+1), w.y (j+2,j+3)
                    unsigned we = (lane & 32) ? w.y : w.x;
                    unsigned ps = (we >> shsel) & 0xffffu;
                    uint4 u = *(const uint4*)(xh + ((size_t)ps << 9) + lhb);
                    pkaccu(ac0, u.x); pkaccu(ac1, u.y);
                    pkaccu(ac2, u.z); pkaccu(ac3, u.w);
                }
                {   // pixels j+4..j+7: ids in w.z, w.w
                    unsigned we = (lane & 32) ? w.w : w.z;
                    unsigned ps = (we >> shsel) & 0xffffu;
                    uint4 u = *(const uint4*)(xh + ((size_t)ps << 9) + lhb);
                    pkaccu(ac0, u.x); pkaccu(ac1, u.y);
                    pkaccu(ac2, u.z); pkaccu(ac3, u.w);
                }
                if (!more) break;
                w = wn; j = jn;
            }
        }
        // combine across the 4 pixel-residue lane groups (2 shfl_xor rounds)
        float rs[8] = {ac0.x, ac0.y, ac1.x, ac1.y, ac2.x, ac2.y, ac3.x, ac3.y};
#pragma unroll
        for (int c = 0; c < 8; ++c) {
            rs[c] += __shfl_xor(rs[c], 16);
            rs[c] += __shfl_xor(rs[c], 32);
        }
        if (lane < 16) {
            uint4 o;
            o.x = (unsigned)f2b(rs[0]) | ((unsigned)f2b(rs[1]) << 16);
            o.y = (unsigned)f2b(rs[2]) | ((unsigned)f2b(rs[3]) << 16);
            o.z = (unsigned)f2b(rs[4]) | ((unsigned)f2b(rs[5]) << 16);
            o.w = (unsigned)f2b(rs[6]) | ((unsigned)f2b(rs[7]) << 16);
            *(uint4*)(ht0 + obase + (size_t)r * NC + nl * 8) = o;
        }
    }
}

// ---- depthwise (9,1) conv v2: vectorized uint2 (4 nc/thread, 8 B/lane).
// Wave = one r-row (64 lanes x 8 B = 512 B per load instr vs 128 B scalar).
// Block: 4 r-rows x 64 nc-quads, 12 output angles (+8 halo window v[20]).
__global__ __launch_bounds__(256) void k_conv1(const ushort_t* __restrict__ ht0,
                                               const float* __restrict__ w1,
                                               const float* __restrict__ b1,
                                               ushort_t* __restrict__ bufA) {
    int t = threadIdx.x;
    int g = t & 63;                  // nc-quad: nc0 = g*4
    int rr = t >> 6;                 // 0..3
    int r = blockIdx.x * 4 + rr;     // 0..183
    int rc = r < R_BINS ? r : (R_BINS - 1);
    int a0 = blockIdx.y * 12;        // output angle base (real coords)
    int nc0 = g * 4;
    int ch0 = nc0 & 63;
    float wr[9][4];
#pragma unroll
    for (int k = 0; k < 9; ++k)
#pragma unroll
        for (int j = 0; j < 4; ++j) wr[k][j] = w1[(ch0 + j) * 9 + k];
    float bb[4];
#pragma unroll
    for (int j = 0; j < 4; ++j) bb[j] = b1[ch0 + j];
    const ushort_t* ip = ht0 + ((size_t)a0 * R_BINS + rc) * NC + nc0;
    uint2 v[20];
#pragma unroll
    for (int j = 0; j < 20; ++j)
        v[j] = *(const uint2*)(ip + (size_t)j * (R_BINS * NC));
    ushort_t* op = bufA + ((size_t)(a0 + 4) * R_BINS + rc) * NC + nc0;
    bool wok = (r < R_BINS);
#pragma unroll
    for (int i = 0; i < 12; ++i) {
        float s0 = bb[0], s1 = bb[1], s2 = bb[2], s3 = bb[3];
#pragma unroll
        for (int k = 0; k < 9; ++k) {
            unsigned d0 = v[i + k].x, d1 = v[i + k].y;
            s0 = fmaf(u2f(d0 << 16),          wr[k][0], s0);
            s1 = fmaf(u2f(d0 & 0xffff0000u),  wr[k][1], s1);
            s2 = fmaf(u2f(d1 << 16),          wr[k][2], s2);
            s3 = fmaf(u2f(d1 & 0xffff0000u),  wr[k][3], s3);
        }
        if (wok) {
            uint2 o;
            o.x = (unsigned)f2b(fmaxf(s0, 0.f)) | ((unsigned)f2b(fmaxf(s1, 0.f)) << 16);
            o.y = (unsigned)f2b(fmaxf(s2, 0.f)) | ((unsigned)f2b(fmaxf(s3, 0.f)) << 16);
            *(uint2*)(op + (size_t)i * (R_BINS * NC)) = o;
        }
    }
}

// ---- dense (9,1) conv as MFMA GEMM: B staged in LDS, 64 rows/wave ----
__global__ __launch_bounds__(256) void k_gemm(const ushort_t* __restrict__ in,
                                              const ushort_t* __restrict__ wb,
                                              const float* __restrict__ bias,
                                              ushort_t* __restrict__ out,
                                              int outRowOff) {
    __shared__ ushort_t Bs[36864];   // 73.7 KB -> 2 blocks/CU
    int t = threadIdx.x, lane = t & 63, wv = t >> 6;
    {
        const uint4* src = (const uint4*)wb;
        uint4* dst = (uint4*)Bs;
        for (int i = t; i < 36864 / 8; i += 256) dst[i] = src[i];
    }
    __syncthreads();
    int m = lane & 15, q = lane >> 4;
    int n = blockIdx.y;
    int rowBase = blockIdx.x * 256 + wv * 64;
    const ushort_t* inN = in + n * 64;
    size_t rof[4];
#pragma unroll
    for (int tl = 0; tl < 4; ++tl) {
        int row = rowBase + tl * 16 + m;
        int rowc = row < MROWS ? row : (MROWS - 1);
        rof[tl] = (size_t)rowc * NC;
    }
    float4v acc[4][4];
#pragma unroll
    for (int tl = 0; tl < 4; ++tl)
#pragma unroll
        for (int i = 0; i < 4; ++i) acc[tl][i] = (float4v){0.f, 0.f, 0.f, 0.f};

#pragma unroll
    for (int k = 0; k < 9; ++k) {
#pragma unroll
        for (int h = 0; h < 2; ++h) {
            const ushort_t* base = inN + (size_t)k * (R_BINS * NC) + h * 32 + q * 8;
            short8 af0 = *(const short8*)(base + rof[0]);
            short8 af1 = *(const short8*)(base + rof[1]);
            short8 af2 = *(const short8*)(base + rof[2]);
            short8 af3 = *(const short8*)(base + rof[3]);
            const ushort_t* bl = Bs + (size_t)((k * 2 + h) * 4) * 512 + lane * 8;
            short8 b0 = *(const short8*)(bl);
            short8 b1v = *(const short8*)(bl + 512);
            short8 b2v = *(const short8*)(bl + 1024);
            short8 b3v = *(const short8*)(bl + 1536);
            acc[0][0] = __builtin_amdgcn_mfma_f32_16x16x32_bf16(af0, b0, acc[0][0], 0, 0, 0);
            acc[0][1] = __builtin_amdgcn_mfma_f32_16x16x32_bf16(af0, b1v, acc[0][1], 0, 0, 0);
            acc[0][2] = __builtin_amdgcn_mfma_f32_16x16x32_bf16(af0, b2v, acc[0][2], 0, 0, 0);
            acc[0][3] = __builtin_amdgcn_mfma_f32_16x16x32_bf16(af0, b3v, acc[0][3], 0, 0, 0);
            acc[1][0] = __builtin_amdgcn_mfma_f32_16x16x32_bf16(af1, b0, acc[1][0], 0, 0, 0);
            acc[1][1] = __builtin_amdgcn_mfma_f32_16x16x32_bf16(af1, b1v, acc[1][1], 0, 0, 0);
            acc[1][2] = __builtin_amdgcn_mfma_f32_16x16x32_bf16(af1, b2v, acc[1][2], 0, 0, 0);
            acc[1][3] = __builtin_amdgcn_mfma_f32_16x16x32_bf16(af1, b3v, acc[1][3], 0, 0, 0);
            acc[2][0] = __builtin_amdgcn_mfma_f32_16x16x32_bf16(af2, b0, acc[2][0], 0, 0, 0);
            acc[2][1] = __builtin_amdgcn_mfma_f32_16x16x32_bf16(af2, b1v, acc[2][1], 0, 0, 0);
            acc[2][2] = __builtin_amdgcn_mfma_f32_16x16x32_bf16(af2, b2v, acc[2][2], 0, 0, 0);
            acc[2][3] = __builtin_amdgcn_mfma_f32_16x16x32_bf16(af2, b3v, acc[2][3], 0, 0, 0);
            acc[3][0] = __builtin_amdgcn_mfma_f32_16x16x32_bf16(af3, b0, acc[3][0], 0, 0, 0);
            acc[3][1] = __builtin_amdgcn_mfma_f32_16x16x32_bf16(af3, b1v, acc[3][1], 0, 0, 0);
            acc[3][2] = __builtin_amdgcn_mfma_f32_16x16x32_bf16(af3, b2v, acc[3][2], 0, 0, 0);
            acc[3][3] = __builtin_amdgcn_mfma_f32_16x16x32_bf16(af3, b3v, acc[3][3], 0, 0, 0);
        }
    }

    ushort_t* outN = out + n * 64;
#pragma unroll
    for (int tl = 0; tl < 4; ++tl) {
#pragma unroll
        for (int cot = 0; cot < 4; ++cot) {
            int co = cot * 16 + m;
            float bv = bias[co];
#pragma unroll
            for (int i = 0; i < 4; ++i) {
                int rowD = rowBase + tl * 16 + q * 4 + i;
                float v = fmaxf(acc[tl][cot][i] + bv, 0.f);
                if (rowD < MROWS) outN[(size_t)(rowD + outRowOff) * NC + co] = f2b(v);
            }
        }
    }
}

// ---- inverse DHT v7 (round-5 measured config): depth-3 modulo-scheduled
// register pipeline, 16B/lane loads, pkacc accumulate, no barriers in loop ----
union SharedIdht {
    int rhoL[A_BINS * 32];          // 23040 B, [a][px]
    float tile[2 * 256 * 33];       // 67584 B, [grp][nc][px] (used after loop)
};

#define IDHT_LOAD(S, ang) do { \
    int4 rv0_ = *(const int4*)&u.rhoL[(ang) * 32 + wq * 8]; \
    int4 rv1_ = *(const int4*)&u.rhoL[(ang) * 32 + wq * 8 + 4]; \
    const char* bA_ = (const char*)buf3 + (size_t)(ang) * (R_BINS * NC * 2); \
    { unsigned r_ = (unsigned)(h ? rv0_.y : rv0_.x); S[0] = *(const uint4*)(bA_ + ((size_t)r_ << 9) + lhb); } \
    { unsigned r_ = (unsigned)(h ? rv0_.w : rv0_.z); S[1] = *(const uint4*)(bA_ + ((size_t)r_ << 9) + lhb); } \
    { unsigned r_ = (unsigned)(h ? rv1_.y : rv1_.x); S[2] = *(const uint4*)(bA_ + ((size_t)r_ << 9) + lhb); } \
    { unsigned r_ = (unsigned)(h ? rv1_.w : rv1_.z); S[3] = *(const uint4*)(bA_ + ((size_t)r_ << 9) + lhb); } \
    } while (0)

#define IDHT_CONSUME(S) do { \
    _Pragma("unroll") \
    for (int p_ = 0; p_ < 4; ++p_) { \
        pkaccu(accp[4 * p_ + 0], S[p_].x); \
        pkaccu(accp[4 * p_ + 1], S[p_].y); \
        pkaccu(accp[4 * p_ + 2], S[p_].z); \
        pkaccu(accp[4 * p_ + 3], S[p_].w); \
    } } while (0)

__global__ __launch_bounds__(512, 2) void k_idht(const ushort_t* __restrict__ buf3,
                                                 const int* __restrict__ rho,
                                                 float* __restrict__ outp) {
    __shared__ SharedIdht u;
    int t = threadIdx.x, lane = t & 63, wv = t >> 6;   // wv 0..7
    int grp = wv >> 2;       // angle half: 0 -> 0..89, 1 -> 90..179
    int wq = wv & 3;         // pixel quad: pixels wq*8 .. wq*8+7
    int P0 = blockIdx.x * 32;
    int h = lane >> 5;                       // pixel parity within pair
    unsigned lhb = (unsigned)(lane & 31) * 16;  // byte offset of my 8 nc
    for (int i = t; i < A_BINS * 32; i += 512) {
        int a = i >> 5, px = i & 31;
        u.rhoL[a * 32 + px] = rho[(size_t)a * HW + P0 + px];
    }
    __syncthreads();
    float2v accp[16];
#pragma unroll
    for (int i = 0; i < 16; ++i) accp[i] = (float2v){0.f, 0.f};
    int a0 = grp * 90;

    uint4 S0[4], S1[4], S2[4];
    IDHT_LOAD(S0, a0);
    IDHT_LOAD(S1, a0 + 1);
    IDHT_LOAD(S2, a0 + 2);
    for (int k = 0; k <= 84; k += 3) {
        IDHT_CONSUME(S0); IDHT_LOAD(S0, a0 + k + 3);
        IDHT_CONSUME(S1); IDHT_LOAD(S1, a0 + k + 4);
        IDHT_CONSUME(S2); IDHT_LOAD(S2, a0 + k + 5);
    }
    IDHT_CONSUME(S0);   // a0+87
    IDHT_CONSUME(S1);   // a0+88
    IDHT_CONSUME(S2);   // a0+89

    __syncthreads();    // all waves done reading rhoL; tile aliases it
#pragma unroll
    for (int p = 0; p < 4; ++p) {
        int px = wq * 8 + p * 2 + h;
#pragma unroll
        for (int cc = 0; cc < 8; ++cc)
            u.tile[(size_t)grp * 8448 + ((lane & 31) * 8 + cc) * 33 + px] =
                accp[4 * p + (cc >> 1)][cc & 1];
    }
    __syncthreads();
    int px = t & 31, nc0 = t >> 5;    // nc0 0..15
    float* on = outp + P0 + px;
#pragma unroll
    for (int k = 0; k < 16; ++k) {
        int nc = nc0 + k * 16;
        on[(size_t)nc * HW] = u.tile[nc * 33 + px] + u.tile[8448 + nc * 33 + px];
    }
}

extern "C" void kernel_launch(void* const* d_in, const int* in_sizes, int n_in,
                              void* d_out, int out_size, void* d_ws, size_t ws_size,
                              hipStream_t stream) {
    const float* x   = (const float*)d_in[0];
    const int*   rho = (const int*)d_in[1];
    const float* w1  = (const float*)d_in[2];
    const float* b1  = (const float*)d_in[3];
    const float* w2  = (const float*)d_in[4];
    const float* b2  = (const float*)d_in[5];
    const float* w3  = (const float*)d_in[6];
    const float* b3  = (const float*)d_in[7];
    float* outp = (float*)d_out;

    char* ws = (char*)d_ws;
    size_t off = 0;
    auto alloc = [&](size_t bytes) -> void* {
        void* p = ws + off;
        off = (off + bytes + 255) & ~(size_t)255;
        return p;
    };
    ushort_t* xT    = (ushort_t*)alloc((size_t)(HW + 8) * NC * 2);       // 8 MB + pad row
    ushort_t* ht0   = (ushort_t*)alloc((size_t)AP * R_BINS * NC * 2);    // 17.5 MB
    ushort_t* bufA  = (ushort_t*)alloc((size_t)AP * R_BINS * NC * 2);    // 17.5 MB
    ushort_t* bufB  = (ushort_t*)alloc((size_t)AP * R_BINS * NC * 2);    // 17.5 MB
    ushort_t* buf3  = (ushort_t*)alloc((size_t)A_BINS * R_BINS * NC * 2);// 16.8 MB
    ushort_t* w2b   = (ushort_t*)alloc(36864 * 2);
    ushort_t* w3b   = (ushort_t*)alloc(36864 * 2);
    int*      offs  = (int*)alloc((size_t)A_BINS * (R_BINS + 1) * 4);    // 132 KB
    ushort_t* plist = (ushort_t*)alloc((size_t)A_BINS * PLSTRIDE * 2);   // 6.4 MB

    k_prep<<<1517, 256, 0, stream>>>(x, xT, ht0, bufA, bufB, w2, w3, w2b, w3b,
                                     rho, offs, plist);
    k_dht_g7<<<dim3(360, 16), 256, 0, stream>>>(xT, offs, plist, ht0);
    k_conv1<<<dim3(46, 15), 256, 0, stream>>>(ht0, w1, b1, bufA);
    k_gemm<<<dim3(128, NB), 256, 0, stream>>>(bufA, w2b, b2, bufB, 728);
    k_gemm<<<dim3(128, NB), 256, 0, stream>>>(bufB, w3b, b3, buf3, 0);
    k_idht<<<dim3(512), 512, 0, stream>>>(buf3, rho, outp);
}

// Round 10
// 310.255 us; speedup vs baseline: 1.2082x; 1.0085x over previous
//
#include <hip/hip_runtime.h>

typedef unsigned short ushort_t;
typedef __attribute__((ext_vector_type(8))) short short8;
typedef __attribute__((ext_vector_type(4))) float float4v;
typedef __attribute__((ext_vector_type(2))) float float2v;

#define HW 16384
#define A_BINS 180
#define R_BINS 182
#define AP 188              // A padded by 4 each side
#define CCH 64
#define NB 4
#define NC 256              // NB*CCH, nc-major inner dim of hough buffers
#define MROWS (A_BINS * R_BINS)      // 32760
#define MPROWS (AP * R_BINS)         // 34216
#define PADPX HW            // dummy pixel id -> zeroed row in xT
#define PLSTRIDE 17664      // per-angle plist stride (HW + 182*7 rounded up, %8==0)

static __device__ __forceinline__ float b2f(ushort_t u) {
    union { unsigned u32; float f; } c; c.u32 = ((unsigned)u) << 16; return c.f;
}
static __device__ __forceinline__ float u2f(unsigned u) {
    union { unsigned u32; float f; } c; c.u32 = u; return c.f;
}
static __device__ __forceinline__ ushort_t f2b(float f) {
    union { float f; unsigned u; } c; c.f = f;
    unsigned r = c.u + 0x7fffu + ((c.u >> 16) & 1u);   // RNE
    return (ushort_t)(r >> 16);
}
// packed f32 accumulate: a += {lo(u)<<16, hi(u)} via one VOP3P v_pk_add_f32
static __device__ __forceinline__ void pkaccu(float2v& a, unsigned u) {
    float2v b; b.x = u2f(u << 16); b.y = u2f(u & 0xffff0000u);
    asm("v_pk_add_f32 %0, %1, %0" : "+v"(a) : "v"(b));
}

// ==== fused prep: transpose (blk<1024) | setup (1024..1336) | csr (1337..1516) ====
union PrepShared {
    float tile[64][65];                // 16.6 KB (transpose)
    struct {                           // 42.6 KB (csr)
        int hist[4][R_BINS];
        int tot[R_BINS];
        int offl[R_BINS + 1];
        int cur[4][R_BINS];
        ushort_t sp[PLSTRIDE];
    } c;
};

__global__ __launch_bounds__(256) void k_prep(const float* __restrict__ x,
                                              ushort_t* __restrict__ xT,
                                              ushort_t* __restrict__ ht0,
                                              ushort_t* __restrict__ bufA,
                                              ushort_t* __restrict__ bufB,
                                              const float* __restrict__ w2,
                                              const float* __restrict__ w3,
                                              ushort_t* __restrict__ w2b,
                                              ushort_t* __restrict__ w3b,
                                              const int* __restrict__ rho,
                                              int* __restrict__ offs,
                                              ushort_t* __restrict__ plist) {
    __shared__ PrepShared u;
    int blk = blockIdx.x, t = threadIdx.x;
    if (blk < 1024) {                  // ---------------- transpose ----------------
        int lane = t & 63, g = t >> 6;
        int pBase = (blk & 255) * 64;
        int ncBase = (blk >> 8) * 64;
#pragma unroll
        for (int i = 0; i < 16; ++i) {
            int ncl = g + i * 4;
            u.tile[ncl][lane] = x[(size_t)(ncBase + ncl) * HW + pBase + lane];
        }
        __syncthreads();
#pragma unroll
        for (int i = 0; i < 16; ++i) {
            int pl = g + i * 4;
            xT[(size_t)(pBase + pl) * 256 + ncBase + lane] = f2b(u.tile[lane][pl]);
        }
        return;
    }
    if (blk < 1337) {                  // ---------------- setup ----------------
        int sblk = blk - 1024;         // 0..312
        if (sblk == 312) {             // zero the dummy-pixel row of xT
            if (t < 64) ((uint2*)(xT + (size_t)PADPX * NC))[t] = (uint2){0u, 0u};
            return;
        }
        if (sblk < 24) {
            int b = sblk >> 3, j = sblk & 7;
            int ap = (j < 4) ? j : (184 + (j - 4));
            ushort_t* base = (b == 0 ? ht0 : (b == 1 ? bufA : bufB));
            uint4* p = (uint4*)(base + (size_t)ap * (R_BINS * NC));
            int n16 = R_BINS * NC / 8;
            for (int i = t; i < n16; i += 256) p[i] = (uint4){0, 0, 0, 0};
            return;
        }
        int rep = sblk - 24;               // 0..287
        const float* w = (rep >= 144) ? w3 : w2;
        ushort_t* wb = (rep >= 144) ? w3b : w2b;
        int idx = (rep % 144) * 256 + t;   // 0..36863
        int j = idx & 7;
        int lane = (idx >> 3) & 63;
        int cot = (idx >> 9) & 3;
        int h = (idx >> 11) & 1;
        int k = idx >> 12;
        int co = cot * 16 + (lane & 15);
        int ci = h * 32 + (lane >> 4) * 8 + j;
        wb[idx] = f2b(w[(co * 64 + ci) * 9 + k]);
        return;
    }
    // ---------------- csr: bin -> pixel list, bins padded to %8 ----------------
    int a = blk - 1337, lane = t & 63, wv = t >> 6;
    for (int i = t; i < 4 * R_BINS; i += 256) ((int*)u.c.hist)[i] = 0;
    __syncthreads();
    const int* rA = rho + (size_t)a * HW;
#pragma unroll 4
    for (int i = 0; i < 64; ++i) {
        int r = rA[t + i * 256];
        atomicAdd(&u.c.hist[wv][r], 1);
    }
    __syncthreads();
    if (t < R_BINS) u.c.tot[t] = u.c.hist[0][t] + u.c.hist[1][t] + u.c.hist[2][t] + u.c.hist[3][t];
    __syncthreads();
    if (wv == 0) {                     // wave-parallel exclusive scan of PADDED counts
        int b0 = lane * 3;
        int c0 = (b0     < R_BINS) ? ((u.c.tot[b0]     + 7) & ~7) : 0;
        int c1 = (b0 + 1 < R_BINS) ? ((u.c.tot[b0 + 1] + 7) & ~7) : 0;
        int c2 = (b0 + 2 < R_BINS) ? ((u.c.tot[b0 + 2] + 7) & ~7) : 0;
        int sum = c0 + c1 + c2, inc = sum;
#pragma unroll
        for (int d = 1; d < 64; d <<= 1) {
            int vv = __shfl_up(inc, d);
            if (lane >= d) inc += vv;
        }
        int excl = inc - sum;
        if (b0     < R_BINS) u.c.offl[b0]     = excl;
        if (b0 + 1 < R_BINS) u.c.offl[b0 + 1] = excl + c0;
        if (b0 + 2 < R_BINS) u.c.offl[b0 + 2] = excl + c0 + c1;
        if (lane == 63) u.c.offl[R_BINS] = inc;
    }
    __syncthreads();
    if (t < R_BINS) {
        int b = u.c.offl[t];
        u.c.cur[0][t] = b; b += u.c.hist[0][t];
        u.c.cur[1][t] = b; b += u.c.hist[1][t];
        u.c.cur[2][t] = b; b += u.c.hist[2][t];
        u.c.cur[3][t] = b;
    }
    if (t <= R_BINS) offs[a * (R_BINS + 1) + t] = u.c.offl[t];
    __syncthreads();
#pragma unroll 4
    for (int i = 0; i < 64; ++i) {
        int p = t + i * 256;
        int r = rA[p];
        int pos = atomicAdd(&u.c.cur[wv][r], 1);
        u.c.sp[pos] = (ushort_t)p;
    }
    __syncthreads();
    if (t < R_BINS) {                  // fill pad slots with dummy pixel id
        int base = u.c.offl[t] + u.c.tot[t];
        int pend = u.c.offl[t + 1];
        for (int k = base; k < pend; ++k) u.c.sp[k] = (ushort_t)PADPX;
    }
    __syncthreads();
    int len = u.c.offl[R_BINS];        // multiple of 8
    const uint4* spv = (const uint4*)u.c.sp;
    uint4* plv = (uint4*)(plist + (size_t)a * PLSTRIDE);
    for (int i = t; i < len / 8; i += 256) plv[i] = spv[i];
}

// ---- DHT gather v7 (measured 77 us, unchanged) ----
__global__ __launch_bounds__(256, 4) void k_dht_g7(const ushort_t* __restrict__ xT,
                                                   const int* __restrict__ offs,
                                                   const ushort_t* __restrict__ plist,
                                                   ushort_t* __restrict__ ht0) {
    int ax = blockIdx.x;               // 0..359
    int a = ax >> 1, half = ax & 1;    // v5 mapping (measured-good)
    int part = blockIdx.y;             // 0..15
    int t = threadIdx.x, lane = t & 63, wv = t >> 6;
    int wslot = part * 4 + wv;         // 0..63
    int nl = lane & 15;                // 8-nc chunk within the 128-nc half
    unsigned lhb = (unsigned)nl * 16;  // byte offset of my 8 nc
    unsigned shsel = (lane & 16) ? 16u : 0u;
    const char* xh = (const char*)xT + half * 256;   // byte base of my half
    const uint4* plq = (const uint4*)(plist + (size_t)a * PLSTRIDE);
    const int* offA = offs + a * (R_BINS + 1);
    size_t obase = (size_t)(a + 4) * (R_BINS * NC) + half * 128;
    for (int r = wslot; r < R_BINS; r += 64) {
        int off = __builtin_amdgcn_readfirstlane(offA[r]);
        int end = __builtin_amdgcn_readfirstlane(offA[r + 1]);
        float2v ac0 = (float2v){0.f, 0.f}, ac1 = (float2v){0.f, 0.f};
        float2v ac2 = (float2v){0.f, 0.f}, ac3 = (float2v){0.f, 0.f};
        int j = off;
        if (j < end) {
            uint4 w = plq[j >> 3];
            for (;;) {
                int jn = j + 8;
                uint4 wn = (uint4){0u, 0u, 0u, 0u};
                bool more = jn < end;
                if (more) wn = plq[jn >> 3];
                {   // pixels j..j+3: ids in w.x (j,j+1), w.y (j+2,j+3)
                    unsigned we = (lane & 32) ? w.y : w.x;
                    unsigned ps = (we >> shsel) & 0xffffu;
                    uint4 u = *(const uint4*)(xh + ((size_t)ps << 9) + lhb);
                    pkaccu(ac0, u.x); pkaccu(ac1, u.y);
                    pkaccu(ac2, u.z); pkaccu(ac3, u.w);
                }
                {   // pixels j+4..j+7: ids in w.z, w.w
                    unsigned we = (lane & 32) ? w.w : w.z;
                    unsigned ps = (we >> shsel) & 0xffffu;
                    uint4 u = *(const uint4*)(xh + ((size_t)ps << 9) + lhb);
                    pkaccu(ac0, u.x); pkaccu(ac1, u.y);
                    pkaccu(ac2, u.z); pkaccu(ac3, u.w);
                }
                if (!more) break;
                w = wn; j = jn;
            }
        }
        // combine across the 4 pixel-residue lane groups (2 shfl_xor rounds)
        float rs[8] = {ac0.x, ac0.y, ac1.x, ac1.y, ac2.x, ac2.y, ac3.x, ac3.y};
#pragma unroll
        for (int c = 0; c < 8; ++c) {
            rs[c] += __shfl_xor(rs[c], 16);
            rs[c] += __shfl_xor(rs[c], 32);
        }
        if (lane < 16) {
            uint4 o;
            o.x = (unsigned)f2b(rs[0]) | ((unsigned)f2b(rs[1]) << 16);
            o.y = (unsigned)f2b(rs[2]) | ((unsigned)f2b(rs[3]) << 16);
            o.z = (unsigned)f2b(rs[4]) | ((unsigned)f2b(rs[5]) << 16);
            o.w = (unsigned)f2b(rs[6]) | ((unsigned)f2b(rs[7]) << 16);
            *(uint4*)(ht0 + obase + (size_t)r * NC + nl * 8) = o;
        }
    }
}

// ---- depthwise (9,1) conv v2: vectorized uint2 (4 nc/thread, 8 B/lane) ----
__global__ __launch_bounds__(256) void k_conv1(const ushort_t* __restrict__ ht0,
                                               const float* __restrict__ w1,
                                               const float* __restrict__ b1,
                                               ushort_t* __restrict__ bufA) {
    int t = threadIdx.x;
    int g = t & 63;                  // nc-quad: nc0 = g*4
    int rr = t >> 6;                 // 0..3
    int r = blockIdx.x * 4 + rr;     // 0..183
    int rc = r < R_BINS ? r : (R_BINS - 1);
    int a0 = blockIdx.y * 12;        // output angle base (real coords)
    int nc0 = g * 4;
    int ch0 = nc0 & 63;
    float wr[9][4];
#pragma unroll
    for (int k = 0; k < 9; ++k)
#pragma unroll
        for (int j = 0; j < 4; ++j) wr[k][j] = w1[(ch0 + j) * 9 + k];
    float bb[4];
#pragma unroll
    for (int j = 0; j < 4; ++j) bb[j] = b1[ch0 + j];
    const ushort_t* ip = ht0 + ((size_t)a0 * R_BINS + rc) * NC + nc0;
    uint2 v[20];
#pragma unroll
    for (int j = 0; j < 20; ++j)
        v[j] = *(const uint2*)(ip + (size_t)j * (R_BINS * NC));
    ushort_t* op = bufA + ((size_t)(a0 + 4) * R_BINS + rc) * NC + nc0;
    bool wok = (r < R_BINS);
#pragma unroll
    for (int i = 0; i < 12; ++i) {
        float s0 = bb[0], s1 = bb[1], s2 = bb[2], s3 = bb[3];
#pragma unroll
        for (int k = 0; k < 9; ++k) {
            unsigned d0 = v[i + k].x, d1 = v[i + k].y;
            s0 = fmaf(u2f(d0 << 16),          wr[k][0], s0);
            s1 = fmaf(u2f(d0 & 0xffff0000u),  wr[k][1], s1);
            s2 = fmaf(u2f(d1 << 16),          wr[k][2], s2);
            s3 = fmaf(u2f(d1 & 0xffff0000u),  wr[k][3], s3);
        }
        if (wok) {
            uint2 o;
            o.x = (unsigned)f2b(fmaxf(s0, 0.f)) | ((unsigned)f2b(fmaxf(s1, 0.f)) << 16);
            o.y = (unsigned)f2b(fmaxf(s2, 0.f)) | ((unsigned)f2b(fmaxf(s3, 0.f)) << 16);
            *(uint2*)(op + (size_t)i * (R_BINS * NC)) = o;
        }
    }
}

// ---- dense (9,1) conv as MFMA GEMM v2: B read directly from global (73.7 KB
// total, identical across all blocks -> L1/L2-resident). No LDS, no staging
// barrier -> occupancy 2 -> 3 blocks/CU and a leaner inner loop.
__global__ __launch_bounds__(256) void k_gemm(const ushort_t* __restrict__ in,
                                              const ushort_t* __restrict__ wb,
                                              const float* __restrict__ bias,
                                              ushort_t* __restrict__ out,
                                              int outRowOff) {
    int t = threadIdx.x, lane = t & 63, wv = t >> 6;
    int m = lane & 15, q = lane >> 4;
    int n = blockIdx.y;
    int rowBase = blockIdx.x * 256 + wv * 64;
    const ushort_t* inN = in + n * 64;
    size_t rof[4];
#pragma unroll
    for (int tl = 0; tl < 4; ++tl) {
        int row = rowBase + tl * 16 + m;
        int rowc = row < MROWS ? row : (MROWS - 1);
        rof[tl] = (size_t)rowc * NC;
    }
    float4v acc[4][4];
#pragma unroll
    for (int tl = 0; tl < 4; ++tl)
#pragma unroll
        for (int i = 0; i < 4; ++i) acc[tl][i] = (float4v){0.f, 0.f, 0.f, 0.f};

#pragma unroll
    for (int k = 0; k < 9; ++k) {
#pragma unroll
        for (int h = 0; h < 2; ++h) {
            const ushort_t* base = inN + (size_t)k * (R_BINS * NC) + h * 32 + q * 8;
            short8 af0 = *(const short8*)(base + rof[0]);
            short8 af1 = *(const short8*)(base + rof[1]);
            short8 af2 = *(const short8*)(base + rof[2]);
            short8 af3 = *(const short8*)(base + rof[3]);
            const ushort_t* bl = wb + (size_t)((k * 2 + h) * 4) * 512 + lane * 8;
            short8 b0 = *(const short8*)(bl);
            short8 b1v = *(const short8*)(bl + 512);
            short8 b2v = *(const short8*)(bl + 1024);
            short8 b3v = *(const short8*)(bl + 1536);
            acc[0][0] = __builtin_amdgcn_mfma_f32_16x16x32_bf16(af0, b0, acc[0][0], 0, 0, 0);
            acc[0][1] = __builtin_amdgcn_mfma_f32_16x16x32_bf16(af0, b1v, acc[0][1], 0, 0, 0);
            acc[0][2] = __builtin_amdgcn_mfma_f32_16x16x32_bf16(af0, b2v, acc[0][2], 0, 0, 0);
            acc[0][3] = __builtin_amdgcn_mfma_f32_16x16x32_bf16(af0, b3v, acc[0][3], 0, 0, 0);
            acc[1][0] = __builtin_amdgcn_mfma_f32_16x16x32_bf16(af1, b0, acc[1][0], 0, 0, 0);
            acc[1][1] = __builtin_amdgcn_mfma_f32_16x16x32_bf16(af1, b1v, acc[1][1], 0, 0, 0);
            acc[1][2] = __builtin_amdgcn_mfma_f32_16x16x32_bf16(af1, b2v, acc[1][2], 0, 0, 0);
            acc[1][3] = __builtin_amdgcn_mfma_f32_16x16x32_bf16(af1, b3v, acc[1][3], 0, 0, 0);
            acc[2][0] = __builtin_amdgcn_mfma_f32_16x16x32_bf16(af2, b0, acc[2][0], 0, 0, 0);
            acc[2][1] = __builtin_amdgcn_mfma_f32_16x16x32_bf16(af2, b1v, acc[2][1], 0, 0, 0);
            acc[2][2] = __builtin_amdgcn_mfma_f32_16x16x32_bf16(af2, b2v, acc[2][2], 0, 0, 0);
            acc[2][3] = __builtin_amdgcn_mfma_f32_16x16x32_bf16(af2, b3v, acc[2][3], 0, 0, 0);
            acc[3][0] = __builtin_amdgcn_mfma_f32_16x16x32_bf16(af3, b0, acc[3][0], 0, 0, 0);
            acc[3][1] = __builtin_amdgcn_mfma_f32_16x16x32_bf16(af3, b1v, acc[3][1], 0, 0, 0);
            acc[3][2] = __builtin_amdgcn_mfma_f32_16x16x32_bf16(af3, b2v, acc[3][2], 0, 0, 0);
            acc[3][3] = __builtin_amdgcn_mfma_f32_16x16x32_bf16(af3, b3v, acc[3][3], 0, 0, 0);
        }
    }

    ushort_t* outN = out + n * 64;
#pragma unroll
    for (int tl = 0; tl < 4; ++tl) {
#pragma unroll
        for (int cot = 0; cot < 4; ++cot) {
            int co = cot * 16 + m;
            float bv = bias[co];
#pragma unroll
            for (int i = 0; i < 4; ++i) {
                int rowD = rowBase + tl * 16 + q * 4 + i;
                float v = fmaxf(acc[tl][cot][i] + bv, 0.f);
                if (rowD < MROWS) outN[(size_t)(rowD + outRowOff) * NC + co] = f2b(v);
            }
        }
    }
}

// ---- inverse DHT v7 (measured config): depth-3 modulo-scheduled register
// pipeline, 16B/lane loads, pkacc accumulate, no barriers in loop ----
union SharedIdht {
    int rhoL[A_BINS * 32];          // 23040 B, [a][px]
    float tile[2 * 256 * 33];       // 67584 B, [grp][nc][px] (used after loop)
};

#define IDHT_LOAD(S, ang) do { \
    int4 rv0_ = *(const int4*)&u.rhoL[(ang) * 32 + wq * 8]; \
    int4 rv1_ = *(const int4*)&u.rhoL[(ang) * 32 + wq * 8 + 4]; \
    const char* bA_ = (const char*)buf3 + (size_t)(ang) * (R_BINS * NC * 2); \
    { unsigned r_ = (unsigned)(h ? rv0_.y : rv0_.x); S[0] = *(const uint4*)(bA_ + ((size_t)r_ << 9) + lhb); } \
    { unsigned r_ = (unsigned)(h ? rv0_.w : rv0_.z); S[1] = *(const uint4*)(bA_ + ((size_t)r_ << 9) + lhb); } \
    { unsigned r_ = (unsigned)(h ? rv1_.y : rv1_.x); S[2] = *(const uint4*)(bA_ + ((size_t)r_ << 9) + lhb); } \
    { unsigned r_ = (unsigned)(h ? rv1_.w : rv1_.z); S[3] = *(const uint4*)(bA_ + ((size_t)r_ << 9) + lhb); } \
    } while (0)

#define IDHT_CONSUME(S) do { \
    _Pragma("unroll") \
    for (int p_ = 0; p_ < 4; ++p_) { \
        pkaccu(accp[4 * p_ + 0], S[p_].x); \
        pkaccu(accp[4 * p_ + 1], S[p_].y); \
        pkaccu(accp[4 * p_ + 2], S[p_].z); \
        pkaccu(accp[4 * p_ + 3], S[p_].w); \
    } } while (0)

__global__ __launch_bounds__(512, 2) void k_idht(const ushort_t* __restrict__ buf3,
                                                 const int* __restrict__ rho,
                                                 float* __restrict__ outp) {
    __shared__ SharedIdht u;
    int t = threadIdx.x, lane = t & 63, wv = t >> 6;   // wv 0..7
    int grp = wv >> 2;       // angle half: 0 -> 0..89, 1 -> 90..179
    int wq = wv & 3;         // pixel quad: pixels wq*8 .. wq*8+7
    int P0 = blockIdx.x * 32;
    int h = lane >> 5;                       // pixel parity within pair
    unsigned lhb = (unsigned)(lane & 31) * 16;  // byte offset of my 8 nc
    for (int i = t; i < A_BINS * 32; i += 512) {
        int a = i >> 5, px = i & 31;
        u.rhoL[a * 32 + px] = rho[(size_t)a * HW + P0 + px];
    }
    __syncthreads();
    float2v accp[16];
#pragma unroll
    for (int i = 0; i < 16; ++i) accp[i] = (float2v){0.f, 0.f};
    int a0 = grp * 90;

    uint4 S0[4], S1[4], S2[4];
    IDHT_LOAD(S0, a0);
    IDHT_LOAD(S1, a0 + 1);
    IDHT_LOAD(S2, a0 + 2);
    for (int k = 0; k <= 84; k += 3) {
        IDHT_CONSUME(S0); IDHT_LOAD(S0, a0 + k + 3);
        IDHT_CONSUME(S1); IDHT_LOAD(S1, a0 + k + 4);
        IDHT_CONSUME(S2); IDHT_LOAD(S2, a0 + k + 5);
    }
    IDHT_CONSUME(S0);   // a0+87
    IDHT_CONSUME(S1);   // a0+88
    IDHT_CONSUME(S2);   // a0+89

    __syncthreads();    // all waves done reading rhoL; tile aliases it
#pragma unroll
    for (int p = 0; p < 4; ++p) {
        int px = wq * 8 + p * 2 + h;
#pragma unroll
        for (int cc = 0; cc < 8; ++cc)
            u.tile[(size_t)grp * 8448 + ((lane & 31) * 8 + cc) * 33 + px] =
                accp[4 * p + (cc >> 1)][cc & 1];
    }
    __syncthreads();
    int px = t & 31, nc0 = t >> 5;    // nc0 0..15
    float* on = outp + P0 + px;
#pragma unroll
    for (int k = 0; k < 16; ++k) {
        int nc = nc0 + k * 16;
        on[(size_t)nc * HW] = u.tile[nc * 33 + px] + u.tile[8448 + nc * 33 + px];
    }
}

extern "C" void kernel_launch(void* const* d_in, const int* in_sizes, int n_in,
                              void* d_out, int out_size, void* d_ws, size_t ws_size,
                              hipStream_t stream) {
    const float* x   = (const float*)d_in[0];
    const int*   rho = (const int*)d_in[1];
    const float* w1  = (const float*)d_in[2];
    const float* b1  = (const float*)d_in[3];
    const float* w2  = (const float*)d_in[4];
    const float* b2  = (const float*)d_in[5];
    const float* w3  = (const float*)d_in[6];
    const float* b3  = (const float*)d_in[7];
    float* outp = (float*)d_out;

    char* ws = (char*)d_ws;
    size_t off = 0;
    auto alloc = [&](size_t bytes) -> void* {
        void* p = ws + off;
        off = (off + bytes + 255) & ~(size_t)255;
        return p;
    };
    ushort_t* xT    = (ushort_t*)alloc((size_t)(HW + 8) * NC * 2);       // 8 MB + pad row
    ushort_t* ht0   = (ushort_t*)alloc((size_t)AP * R_BINS * NC * 2);    // 17.5 MB
    ushort_t* bufA  = (ushort_t*)alloc((size_t)AP * R_BINS * NC * 2);    // 17.5 MB
    ushort_t* bufB  = (ushort_t*)alloc((size_t)AP * R_BINS * NC * 2);    // 17.5 MB
    ushort_t* buf3  = (ushort_t*)alloc((size_t)A_BINS * R_BINS * NC * 2);// 16.8 MB
    ushort_t* w2b   = (ushort_t*)alloc(36864 * 2);
    ushort_t* w3b   = (ushort_t*)alloc(36864 * 2);
    int*      offs  = (int*)alloc((size_t)A_BINS * (R_BINS + 1) * 4);    // 132 KB
    ushort_t* plist = (ushort_t*)alloc((size_t)A_BINS * PLSTRIDE * 2);   // 6.4 MB

    k_prep<<<1517, 256, 0, stream>>>(x, xT, ht0, bufA, bufB, w2, w3, w2b, w3b,
                                     rho, offs, plist);
    k_dht_g7<<<dim3(360, 16), 256, 0, stream>>>(xT, offs, plist, ht0);
    k_conv1<<<dim3(46, 15), 256, 0, stream>>>(ht0, w1, b1, bufA);
    k_gemm<<<dim3(128, NB), 256, 0, stream>>>(bufA, w2b, b2, bufB, 728);
    k_gemm<<<dim3(128, NB), 256, 0, stream>>>(bufB, w3b, b3, buf3, 0);
    k_idht<<<dim3(512), 512, 0, stream>>>(buf3, rho, outp);
}

// Round 11
// 308.958 us; speedup vs baseline: 1.2133x; 1.0042x over previous
//
#include <hip/hip_runtime.h>

typedef unsigned short ushort_t;
typedef __attribute__((ext_vector_type(8))) short short8;
typedef __attribute__((ext_vector_type(4))) float float4v;
typedef __attribute__((ext_vector_type(2))) float float2v;

#define HW 16384
#define A_BINS 180
#define R_BINS 182
#define AP 188              // A padded by 4 each side
#define CCH 64
#define NB 4
#define NC 256              // NB*CCH, nc-major inner dim of hough buffers
#define MROWS (A_BINS * R_BINS)      // 32760
#define MPROWS (AP * R_BINS)         // 34216
#define PADPX HW            // dummy pixel id -> zeroed row in xT
#define PLSTRIDE 17664      // per-angle plist stride (HW + 182*7 rounded up, %8==0)

static __device__ __forceinline__ float b2f(ushort_t u) {
    union { unsigned u32; float f; } c; c.u32 = ((unsigned)u) << 16; return c.f;
}
static __device__ __forceinline__ float u2f(unsigned u) {
    union { unsigned u32; float f; } c; c.u32 = u; return c.f;
}
static __device__ __forceinline__ ushort_t f2b(float f) {
    union { float f; unsigned u; } c; c.f = f;
    unsigned r = c.u + 0x7fffu + ((c.u >> 16) & 1u);   // RNE
    return (ushort_t)(r >> 16);
}
// packed f32 accumulate: a += {lo(u)<<16, hi(u)} via one VOP3P v_pk_add_f32
static __device__ __forceinline__ void pkaccu(float2v& a, unsigned u) {
    float2v b; b.x = u2f(u << 16); b.y = u2f(u & 0xffff0000u);
    asm("v_pk_add_f32 %0, %1, %0" : "+v"(a) : "v"(b));
}

// ==== fused prep: transpose (blk<1024) | setup (1024..1336) | csr (1337..1516) ====
union PrepShared {
    float tile[64][65];                // 16.6 KB (transpose)
    struct {                           // 42.6 KB (csr)
        int hist[4][R_BINS];
        int tot[R_BINS];
        int offl[R_BINS + 1];
        int cur[4][R_BINS];
        ushort_t sp[PLSTRIDE];
    } c;
};

__global__ __launch_bounds__(256) void k_prep(const float* __restrict__ x,
                                              ushort_t* __restrict__ xT,
                                              ushort_t* __restrict__ ht0,
                                              ushort_t* __restrict__ bufA,
                                              ushort_t* __restrict__ bufB,
                                              const float* __restrict__ w2,
                                              const float* __restrict__ w3,
                                              ushort_t* __restrict__ w2b,
                                              ushort_t* __restrict__ w3b,
                                              const int* __restrict__ rho,
                                              int* __restrict__ offs,
                                              ushort_t* __restrict__ plist) {
    __shared__ PrepShared u;
    int blk = blockIdx.x, t = threadIdx.x;
    if (blk < 1024) {                  // ---------------- transpose ----------------
        int lane = t & 63, g = t >> 6;
        int pBase = (blk & 255) * 64;
        int ncBase = (blk >> 8) * 64;
#pragma unroll
        for (int i = 0; i < 16; ++i) {
            int ncl = g + i * 4;
            u.tile[ncl][lane] = x[(size_t)(ncBase + ncl) * HW + pBase + lane];
        }
        __syncthreads();
#pragma unroll
        for (int i = 0; i < 16; ++i) {
            int pl = g + i * 4;
            xT[(size_t)(pBase + pl) * 256 + ncBase + lane] = f2b(u.tile[lane][pl]);
        }
        return;
    }
    if (blk < 1337) {                  // ---------------- setup ----------------
        int sblk = blk - 1024;         // 0..312
        if (sblk == 312) {             // zero the dummy-pixel row of xT
            if (t < 64) ((uint2*)(xT + (size_t)PADPX * NC))[t] = (uint2){0u, 0u};
            return;
        }
        if (sblk < 24) {
            int b = sblk >> 3, j = sblk & 7;
            int ap = (j < 4) ? j : (184 + (j - 4));
            ushort_t* base = (b == 0 ? ht0 : (b == 1 ? bufA : bufB));
            uint4* p = (uint4*)(base + (size_t)ap * (R_BINS * NC));
            int n16 = R_BINS * NC / 8;
            for (int i = t; i < n16; i += 256) p[i] = (uint4){0, 0, 0, 0};
            return;
        }
        int rep = sblk - 24;               // 0..287
        const float* w = (rep >= 144) ? w3 : w2;
        ushort_t* wb = (rep >= 144) ? w3b : w2b;
        int idx = (rep % 144) * 256 + t;   // 0..36863
        int j = idx & 7;
        int lane = (idx >> 3) & 63;
        int cot = (idx >> 9) & 3;
        int h = (idx >> 11) & 1;
        int k = idx >> 12;
        int co = cot * 16 + (lane & 15);
        int ci = h * 32 + (lane >> 4) * 8 + j;
        wb[idx] = f2b(w[(co * 64 + ci) * 9 + k]);
        return;
    }
    // ---------------- csr: bin -> pixel list, bins padded to %8 ----------------
    int a = blk - 1337, lane = t & 63, wv = t >> 6;
    for (int i = t; i < 4 * R_BINS; i += 256) ((int*)u.c.hist)[i] = 0;
    __syncthreads();
    const int* rA = rho + (size_t)a * HW;
#pragma unroll 4
    for (int i = 0; i < 64; ++i) {
        int r = rA[t + i * 256];
        atomicAdd(&u.c.hist[wv][r], 1);
    }
    __syncthreads();
    if (t < R_BINS) u.c.tot[t] = u.c.hist[0][t] + u.c.hist[1][t] + u.c.hist[2][t] + u.c.hist[3][t];
    __syncthreads();
    if (wv == 0) {                     // wave-parallel exclusive scan of PADDED counts
        int b0 = lane * 3;
        int c0 = (b0     < R_BINS) ? ((u.c.tot[b0]     + 7) & ~7) : 0;
        int c1 = (b0 + 1 < R_BINS) ? ((u.c.tot[b0 + 1] + 7) & ~7) : 0;
        int c2 = (b0 + 2 < R_BINS) ? ((u.c.tot[b0 + 2] + 7) & ~7) : 0;
        int sum = c0 + c1 + c2, inc = sum;
#pragma unroll
        for (int d = 1; d < 64; d <<= 1) {
            int vv = __shfl_up(inc, d);
            if (lane >= d) inc += vv;
        }
        int excl = inc - sum;
        if (b0     < R_BINS) u.c.offl[b0]     = excl;
        if (b0 + 1 < R_BINS) u.c.offl[b0 + 1] = excl + c0;
        if (b0 + 2 < R_BINS) u.c.offl[b0 + 2] = excl + c0 + c1;
        if (lane == 63) u.c.offl[R_BINS] = inc;
    }
    __syncthreads();
    if (t < R_BINS) {
        int b = u.c.offl[t];
        u.c.cur[0][t] = b; b += u.c.hist[0][t];
        u.c.cur[1][t] = b; b += u.c.hist[1][t];
        u.c.cur[2][t] = b; b += u.c.hist[2][t];
        u.c.cur[3][t] = b;
    }
    if (t <= R_BINS) offs[a * (R_BINS + 1) + t] = u.c.offl[t];
    __syncthreads();
#pragma unroll 4
    for (int i = 0; i < 64; ++i) {
        int p = t + i * 256;
        int r = rA[p];
        int pos = atomicAdd(&u.c.cur[wv][r], 1);
        u.c.sp[pos] = (ushort_t)p;
    }
    __syncthreads();
    if (t < R_BINS) {                  // fill pad slots with dummy pixel id
        int base = u.c.offl[t] + u.c.tot[t];
        int pend = u.c.offl[t + 1];
        for (int k = base; k < pend; ++k) u.c.sp[k] = (ushort_t)PADPX;
    }
    __syncthreads();
    int len = u.c.offl[R_BINS];        // multiple of 8
    const uint4* spv = (const uint4*)u.c.sp;
    uint4* plv = (uint4*)(plist + (size_t)a * PLSTRIDE);
    for (int i = t; i < len / 8; i += 256) plv[i] = spv[i];
}

// ---- DHT gather v8: v7 + occupancy 4->8 blocks/CU (16 VGPR kernel was
// launch-bound-capped; more waves hide gather latency) + unconditional index
// prefetch (padded PLSTRIDE keeps plq[jn>>3] in-bounds for jn <= end).
__global__ __launch_bounds__(256, 8) void k_dht_g8(const ushort_t* __restrict__ xT,
                                                   const int* __restrict__ offs,
                                                   const ushort_t* __restrict__ plist,
                                                   ushort_t* __restrict__ ht0) {
    int ax = blockIdx.x;               // 0..359
    int a = ax >> 1, half = ax & 1;    // v5 mapping (measured-good)
    int part = blockIdx.y;             // 0..15
    int t = threadIdx.x, lane = t & 63, wv = t >> 6;
    int wslot = part * 4 + wv;         // 0..63
    int nl = lane & 15;                // 8-nc chunk within the 128-nc half
    unsigned lhb = (unsigned)nl * 16;  // byte offset of my 8 nc
    unsigned shsel = (lane & 16) ? 16u : 0u;
    const char* xh = (const char*)xT + half * 256;   // byte base of my half
    const uint4* plq = (const uint4*)(plist + (size_t)a * PLSTRIDE);
    const int* offA = offs + a * (R_BINS + 1);
    size_t obase = (size_t)(a + 4) * (R_BINS * NC) + half * 128;
    for (int r = wslot; r < R_BINS; r += 64) {
        int off = __builtin_amdgcn_readfirstlane(offA[r]);
        int end = __builtin_amdgcn_readfirstlane(offA[r + 1]);
        float2v ac0 = (float2v){0.f, 0.f}, ac1 = (float2v){0.f, 0.f};
        float2v ac2 = (float2v){0.f, 0.f}, ac3 = (float2v){0.f, 0.f};
        int j = off;
        if (j < end) {
            uint4 w = plq[j >> 3];
            for (;;) {
                int jn = j + 8;
                uint4 wn = plq[jn >> 3];   // unconditional: jn<=end<=17656 -> in stride
                {   // pixels j..j+3: ids in w.x (j,j+1), w.y (j+2,j+3)
                    unsigned we = (lane & 32) ? w.y : w.x;
                    unsigned ps = (we >> shsel) & 0xffffu;
                    uint4 u = *(const uint4*)(xh + ((size_t)ps << 9) + lhb);
                    pkaccu(ac0, u.x); pkaccu(ac1, u.y);
                    pkaccu(ac2, u.z); pkaccu(ac3, u.w);
                }
                {   // pixels j+4..j+7: ids in w.z, w.w
                    unsigned we = (lane & 32) ? w.w : w.z;
                    unsigned ps = (we >> shsel) & 0xffffu;
                    uint4 u = *(const uint4*)(xh + ((size_t)ps << 9) + lhb);
                    pkaccu(ac0, u.x); pkaccu(ac1, u.y);
                    pkaccu(ac2, u.z); pkaccu(ac3, u.w);
                }
                if (jn >= end) break;
                w = wn; j = jn;
            }
        }
        // combine across the 4 pixel-residue lane groups (2 shfl_xor rounds)
        float rs[8] = {ac0.x, ac0.y, ac1.x, ac1.y, ac2.x, ac2.y, ac3.x, ac3.y};
#pragma unroll
        for (int c = 0; c < 8; ++c) {
            rs[c] += __shfl_xor(rs[c], 16);
            rs[c] += __shfl_xor(rs[c], 32);
        }
        if (lane < 16) {
            uint4 o;
            o.x = (unsigned)f2b(rs[0]) | ((unsigned)f2b(rs[1]) << 16);
            o.y = (unsigned)f2b(rs[2]) | ((unsigned)f2b(rs[3]) << 16);
            o.z = (unsigned)f2b(rs[4]) | ((unsigned)f2b(rs[5]) << 16);
            o.w = (unsigned)f2b(rs[6]) | ((unsigned)f2b(rs[7]) << 16);
            *(uint4*)(ht0 + obase + (size_t)r * NC + nl * 8) = o;
        }
    }
}

// ---- depthwise (9,1) conv v2: vectorized uint2 (4 nc/thread, 8 B/lane) ----
__global__ __launch_bounds__(256) void k_conv1(const ushort_t* __restrict__ ht0,
                                               const float* __restrict__ w1,
                                               const float* __restrict__ b1,
                                               ushort_t* __restrict__ bufA) {
    int t = threadIdx.x;
    int g = t & 63;                  // nc-quad: nc0 = g*4
    int rr = t >> 6;                 // 0..3
    int r = blockIdx.x * 4 + rr;     // 0..183
    int rc = r < R_BINS ? r : (R_BINS - 1);
    int a0 = blockIdx.y * 12;        // output angle base (real coords)
    int nc0 = g * 4;
    int ch0 = nc0 & 63;
    float wr[9][4];
#pragma unroll
    for (int k = 0; k < 9; ++k)
#pragma unroll
        for (int j = 0; j < 4; ++j) wr[k][j] = w1[(ch0 + j) * 9 + k];
    float bb[4];
#pragma unroll
    for (int j = 0; j < 4; ++j) bb[j] = b1[ch0 + j];
    const ushort_t* ip = ht0 + ((size_t)a0 * R_BINS + rc) * NC + nc0;
    uint2 v[20];
#pragma unroll
    for (int j = 0; j < 20; ++j)
        v[j] = *(const uint2*)(ip + (size_t)j * (R_BINS * NC));
    ushort_t* op = bufA + ((size_t)(a0 + 4) * R_BINS + rc) * NC + nc0;
    bool wok = (r < R_BINS);
#pragma unroll
    for (int i = 0; i < 12; ++i) {
        float s0 = bb[0], s1 = bb[1], s2 = bb[2], s3 = bb[3];
#pragma unroll
        for (int k = 0; k < 9; ++k) {
            unsigned d0 = v[i + k].x, d1 = v[i + k].y;
            s0 = fmaf(u2f(d0 << 16),          wr[k][0], s0);
            s1 = fmaf(u2f(d0 & 0xffff0000u),  wr[k][1], s1);
            s2 = fmaf(u2f(d1 << 16),          wr[k][2], s2);
            s3 = fmaf(u2f(d1 & 0xffff0000u),  wr[k][3], s3);
        }
        if (wok) {
            uint2 o;
            o.x = (unsigned)f2b(fmaxf(s0, 0.f)) | ((unsigned)f2b(fmaxf(s1, 0.f)) << 16);
            o.y = (unsigned)f2b(fmaxf(s2, 0.f)) | ((unsigned)f2b(fmaxf(s3, 0.f)) << 16);
            *(uint2*)(op + (size_t)i * (R_BINS * NC)) = o;
        }
    }
}

// ---- dense (9,1) conv as MFMA GEMM v2: B read directly from global (73.7 KB
// total, identical across all blocks -> L1/L2-resident). No LDS staging.
__global__ __launch_bounds__(256) void k_gemm(const ushort_t* __restrict__ in,
                                              const ushort_t* __restrict__ wb,
                                              const float* __restrict__ bias,
                                              ushort_t* __restrict__ out,
                                              int outRowOff) {
    int t = threadIdx.x, lane = t & 63, wv = t >> 6;
    int m = lane & 15, q = lane >> 4;
    int n = blockIdx.y;
    int rowBase = blockIdx.x * 256 + wv * 64;
    const ushort_t* inN = in + n * 64;
    size_t rof[4];
#pragma unroll
    for (int tl = 0; tl < 4; ++tl) {
        int row = rowBase + tl * 16 + m;
        int rowc = row < MROWS ? row : (MROWS - 1);
        rof[tl] = (size_t)rowc * NC;
    }
    float4v acc[4][4];
#pragma unroll
    for (int tl = 0; tl < 4; ++tl)
#pragma unroll
        for (int i = 0; i < 4; ++i) acc[tl][i] = (float4v){0.f, 0.f, 0.f, 0.f};

#pragma unroll
    for (int k = 0; k < 9; ++k) {
#pragma unroll
        for (int h = 0; h < 2; ++h) {
            const ushort_t* base = inN + (size_t)k * (R_BINS * NC) + h * 32 + q * 8;
            short8 af0 = *(const short8*)(base + rof[0]);
            short8 af1 = *(const short8*)(base + rof[1]);
            short8 af2 = *(const short8*)(base + rof[2]);
            short8 af3 = *(const short8*)(base + rof[3]);
            const ushort_t* bl = wb + (size_t)((k * 2 + h) * 4) * 512 + lane * 8;
            short8 b0 = *(const short8*)(bl);
            short8 b1v = *(const short8*)(bl + 512);
            short8 b2v = *(const short8*)(bl + 1024);
            short8 b3v = *(const short8*)(bl + 1536);
            acc[0][0] = __builtin_amdgcn_mfma_f32_16x16x32_bf16(af0, b0, acc[0][0], 0, 0, 0);
            acc[0][1] = __builtin_amdgcn_mfma_f32_16x16x32_bf16(af0, b1v, acc[0][1], 0, 0, 0);
            acc[0][2] = __builtin_amdgcn_mfma_f32_16x16x32_bf16(af0, b2v, acc[0][2], 0, 0, 0);
            acc[0][3] = __builtin_amdgcn_mfma_f32_16x16x32_bf16(af0, b3v, acc[0][3], 0, 0, 0);
            acc[1][0] = __builtin_amdgcn_mfma_f32_16x16x32_bf16(af1, b0, acc[1][0], 0, 0, 0);
            acc[1][1] = __builtin_amdgcn_mfma_f32_16x16x32_bf16(af1, b1v, acc[1][1], 0, 0, 0);
            acc[1][2] = __builtin_amdgcn_mfma_f32_16x16x32_bf16(af1, b2v, acc[1][2], 0, 0, 0);
            acc[1][3] = __builtin_amdgcn_mfma_f32_16x16x32_bf16(af1, b3v, acc[1][3], 0, 0, 0);
            acc[2][0] = __builtin_amdgcn_mfma_f32_16x16x32_bf16(af2, b0, acc[2][0], 0, 0, 0);
            acc[2][1] = __builtin_amdgcn_mfma_f32_16x16x32_bf16(af2, b1v, acc[2][1], 0, 0, 0);
            acc[2][2] = __builtin_amdgcn_mfma_f32_16x16x32_bf16(af2, b2v, acc[2][2], 0, 0, 0);
            acc[2][3] = __builtin_amdgcn_mfma_f32_16x16x32_bf16(af2, b3v, acc[2][3], 0, 0, 0);
            acc[3][0] = __builtin_amdgcn_mfma_f32_16x16x32_bf16(af3, b0, acc[3][0], 0, 0, 0);
            acc[3][1] = __builtin_amdgcn_mfma_f32_16x16x32_bf16(af3, b1v, acc[3][1], 0, 0, 0);
            acc[3][2] = __builtin_amdgcn_mfma_f32_16x16x32_bf16(af3, b2v, acc[3][2], 0, 0, 0);
            acc[3][3] = __builtin_amdgcn_mfma_f32_16x16x32_bf16(af3, b3v, acc[3][3], 0, 0, 0);
        }
    }

    ushort_t* outN = out + n * 64;
#pragma unroll
    for (int tl = 0; tl < 4; ++tl) {
#pragma unroll
        for (int cot = 0; cot < 4; ++cot) {
            int co = cot * 16 + m;
            float bv = bias[co];
#pragma unroll
            for (int i = 0; i < 4; ++i) {
                int rowD = rowBase + tl * 16 + q * 4 + i;
                float v = fmaxf(acc[tl][cot][i] + bv, 0.f);
                if (rowD < MROWS) outN[(size_t)(rowD + outRowOff) * NC + co] = f2b(v);
            }
        }
    }
}

// ---- inverse DHT v7 (measured ~70 us): depth-3 modulo-scheduled register
// pipeline, 16B/lane loads, pkacc accumulate, no barriers in loop ----
union SharedIdht {
    int rhoL[A_BINS * 32];          // 23040 B, [a][px]
    float tile[2 * 256 * 33];       // 67584 B, [grp][nc][px] (used after loop)
};

#define IDHT_LOAD(S, ang) do { \
    int4 rv0_ = *(const int4*)&u.rhoL[(ang) * 32 + wq * 8]; \
    int4 rv1_ = *(const int4*)&u.rhoL[(ang) * 32 + wq * 8 + 4]; \
    const char* bA_ = (const char*)buf3 + (size_t)(ang) * (R_BINS * NC * 2); \
    { unsigned r_ = (unsigned)(h ? rv0_.y : rv0_.x); S[0] = *(const uint4*)(bA_ + ((size_t)r_ << 9) + lhb); } \
    { unsigned r_ = (unsigned)(h ? rv0_.w : rv0_.z); S[1] = *(const uint4*)(bA_ + ((size_t)r_ << 9) + lhb); } \
    { unsigned r_ = (unsigned)(h ? rv1_.y : rv1_.x); S[2] = *(const uint4*)(bA_ + ((size_t)r_ << 9) + lhb); } \
    { unsigned r_ = (unsigned)(h ? rv1_.w : rv1_.z); S[3] = *(const uint4*)(bA_ + ((size_t)r_ << 9) + lhb); } \
    } while (0)

#define IDHT_CONSUME(S) do { \
    _Pragma("unroll") \
    for (int p_ = 0; p_ < 4; ++p_) { \
        pkaccu(accp[4 * p_ + 0], S[p_].x); \
        pkaccu(accp[4 * p_ + 1], S[p_].y); \
        pkaccu(accp[4 * p_ + 2], S[p_].z); \
        pkaccu(accp[4 * p_ + 3], S[p_].w); \
    } } while (0)

__global__ __launch_bounds__(512, 2) void k_idht(const ushort_t* __restrict__ buf3,
                                                 const int* __restrict__ rho,
                                                 float* __restrict__ outp) {
    __shared__ SharedIdht u;
    int t = threadIdx.x, lane = t & 63, wv = t >> 6;   // wv 0..7
    int grp = wv >> 2;       // angle half: 0 -> 0..89, 1 -> 90..179
    int wq = wv & 3;         // pixel quad: pixels wq*8 .. wq*8+7
    int P0 = blockIdx.x * 32;
    int h = lane >> 5;                       // pixel parity within pair
    unsigned lhb = (unsigned)(lane & 31) * 16;  // byte offset of my 8 nc
    for (int i = t; i < A_BINS * 32; i += 512) {
        int a = i >> 5, px = i & 31;
        u.rhoL[a * 32 + px] = rho[(size_t)a * HW + P0 + px];
    }
    __syncthreads();
    float2v accp[16];
#pragma unroll
    for (int i = 0; i < 16; ++i) accp[i] = (float2v){0.f, 0.f};
    int a0 = grp * 90;

    uint4 S0[4], S1[4], S2[4];
    IDHT_LOAD(S0, a0);
    IDHT_LOAD(S1, a0 + 1);
    IDHT_LOAD(S2, a0 + 2);
    for (int k = 0; k <= 84; k += 3) {
        IDHT_CONSUME(S0); IDHT_LOAD(S0, a0 + k + 3);
        IDHT_CONSUME(S1); IDHT_LOAD(S1, a0 + k + 4);
        IDHT_CONSUME(S2); IDHT_LOAD(S2, a0 + k + 5);
    }
    IDHT_CONSUME(S0);   // a0+87
    IDHT_CONSUME(S1);   // a0+88
    IDHT_CONSUME(S2);   // a0+89

    __syncthreads();    // all waves done reading rhoL; tile aliases it
#pragma unroll
    for (int p = 0; p < 4; ++p) {
        int px = wq * 8 + p * 2 + h;
#pragma unroll
        for (int cc = 0; cc < 8; ++cc)
            u.tile[(size_t)grp * 8448 + ((lane & 31) * 8 + cc) * 33 + px] =
                accp[4 * p + (cc >> 1)][cc & 1];
    }
    __syncthreads();
    int px = t & 31, nc0 = t >> 5;    // nc0 0..15
    float* on = outp + P0 + px;
#pragma unroll
    for (int k = 0; k < 16; ++k) {
        int nc = nc0 + k * 16;
        on[(size_t)nc * HW] = u.tile[nc * 33 + px] + u.tile[8448 + nc * 33 + px];
    }
}

extern "C" void kernel_launch(void* const* d_in, const int* in_sizes, int n_in,
                              void* d_out, int out_size, void* d_ws, size_t ws_size,
                              hipStream_t stream) {
    const float* x   = (const float*)d_in[0];
    const int*   rho = (const int*)d_in[1];
    const float* w1  = (const float*)d_in[2];
    const float* b1  = (const float*)d_in[3];
    const float* w2  = (const float*)d_in[4];
    const float* b2  = (const float*)d_in[5];
    const float* w3  = (const float*)d_in[6];
    const float* b3  = (const float*)d_in[7];
    float* outp = (float*)d_out;

    char* ws = (char*)d_ws;
    size_t off = 0;
    auto alloc = [&](size_t bytes) -> void* {
        void* p = ws + off;
        off = (off + bytes + 255) & ~(size_t)255;
        return p;
    };
    ushort_t* xT    = (ushort_t*)alloc((size_t)(HW + 8) * NC * 2);       // 8 MB + pad row
    ushort_t* ht0   = (ushort_t*)alloc((size_t)AP * R_BINS * NC * 2);    // 17.5 MB
    ushort_t* bufA  = (ushort_t*)alloc((size_t)AP * R_BINS * NC * 2);    // 17.5 MB
    ushort_t* bufB  = (ushort_t*)alloc((size_t)AP * R_BINS * NC * 2);    // 17.5 MB
    ushort_t* buf3  = (ushort_t*)alloc((size_t)A_BINS * R_BINS * NC * 2);// 16.8 MB
    ushort_t* w2b   = (ushort_t*)alloc(36864 * 2);
    ushort_t* w3b   = (ushort_t*)alloc(36864 * 2);
    int*      offs  = (int*)alloc((size_t)A_BINS * (R_BINS + 1) * 4);    // 132 KB
    ushort_t* plist = (ushort_t*)alloc((size_t)A_BINS * PLSTRIDE * 2);   // 6.4 MB

    k_prep<<<1517, 256, 0, stream>>>(x, xT, ht0, bufA, bufB, w2, w3, w2b, w3b,
                                     rho, offs, plist);
    k_dht_g8<<<dim3(360, 16), 256, 0, stream>>>(xT, offs, plist, ht0);
    k_conv1<<<dim3(46, 15), 256, 0, stream>>>(ht0, w1, b1, bufA);
    k_gemm<<<dim3(128, NB), 256, 0, stream>>>(bufA, w2b, b2, bufB, 728);
    k_gemm<<<dim3(128, NB), 256, 0, stream>>>(bufB, w3b, b3, buf3, 0);
    k_idht<<<dim3(512), 512, 0, stream>>>(buf3, rho, outp);
}